// Round 5
// baseline (4421.713 us; speedup 1.0000x reference)
//
#include <hip/hip_runtime.h>
#include <hip/hip_bf16.h>

typedef __hip_bfloat16 bf16;

#define N_B 8
#define N_C 256
#define N_H 4
#define N_N 2304
#define N_ELEM 589824   // N_C * N_N

// ---------------- per-batch mean/rstd, one block per batch ------------------
__global__ __launch_bounds__(256) void stats_dumb(const float* __restrict__ x,
                                                  float* __restrict__ mr) {
  int b = blockIdx.x;
  const float* xb = x + (size_t)b * N_ELEM;
  float s = 0.f, ss = 0.f;
  for (int i = threadIdx.x; i < N_ELEM; i += 256) {
    float v = xb[i];
    s += v; ss += v * v;
  }
  __shared__ float ls[256], lss[256];
  ls[threadIdx.x] = s; lss[threadIdx.x] = ss;
  __syncthreads();
  for (int off = 128; off; off >>= 1) {
    if (threadIdx.x < off) {
      ls[threadIdx.x]  += ls[threadIdx.x + off];
      lss[threadIdx.x] += lss[threadIdx.x + off];
    }
    __syncthreads();
  }
  if (threadIdx.x == 0) {
    float mean = ls[0] * (1.f / (float)N_ELEM);
    float var  = lss[0] * (1.f / (float)N_ELEM) - mean * mean;
    mr[b * 2]     = mean;
    mr[b * 2 + 1] = rsqrtf(var + 1e-5f);
  }
}

// ---------------- materialize xn[b][c][n] (bf16 for footprint only) ---------
__global__ __launch_bounds__(256) void gn_apply(const float* __restrict__ x,
                                                const float* __restrict__ mr,
                                                const float* __restrict__ gnw,
                                                const float* __restrict__ gnb,
                                                bf16* __restrict__ xn) {
  int blk = blockIdx.x;              // 4608 = 8 * 576
  int b = blk / 576, rem = blk % 576;
  float mean = mr[b * 2], rstd = mr[b * 2 + 1];
  int e0 = rem * 1024 + threadIdx.x * 4;   // 4-aligned; 2304 % 4 == 0 so same c
  int c = e0 / N_N;
  float a  = rstd * gnw[c];
  float dd = gnb[c] - mean * a;
  const float* xp = x + (size_t)b * N_ELEM + e0;
  bf16* xo = xn + (size_t)b * N_ELEM + e0;
#pragma unroll
  for (int j = 0; j < 4; ++j) xo[j] = __float2bfloat16(xp[j] * a + dd);
}

// ---------------- dumb QKV: scalar fp32 dots, direct indexing ---------------
// qkv[seg][b][h][n][d], q pre-scaled by 0.125
__global__ __launch_bounds__(256) void qkv_dumb(const float* __restrict__ wqkv,
                                                const bf16* __restrict__ xn,
                                                bf16* __restrict__ qkv) {
  int id = blockIdx.x;               // 6144 = 8 * 768
  int b = id / 768, o = id % 768;
  const float* wr = wqkv + (size_t)o * 256;
  const bf16* xb = xn + (size_t)b * N_ELEM;
  __shared__ float wl[256];
  wl[threadIdx.x] = wr[threadIdx.x];
  __syncthreads();
  float s[9];
#pragma unroll
  for (int t = 0; t < 9; ++t) s[t] = 0.f;
  for (int c = 0; c < 256; ++c) {
    float w = wl[c];
    const bf16* xc = xb + (size_t)c * N_N;
#pragma unroll
    for (int t = 0; t < 9; ++t) {
      int n = threadIdx.x + t * 256;
      s[t] += w * __bfloat162float(xc[n]);
    }
  }
  int seg = o >> 8, h = (o >> 6) & 3, d = o & 63;
  float sc = (seg == 0) ? 0.125f : 1.0f;
  bf16* Out = qkv + ((size_t)seg * N_B * N_H + (size_t)b * N_H + h) * (size_t)N_N * 64;
#pragma unroll
  for (int t = 0; t < 9; ++t) {
    int n = threadIdx.x + t * 256;
    Out[(size_t)n * 64 + d] = __float2bfloat16(s[t] * sc);
  }
}

// ---------------- dumb scalar flash attention (natural exp) -----------------
// thread (qq,pp): query q0+qq; keys pp*16..+15 for scores; d=pp*16..+15 for PV
__global__ __launch_bounds__(256) void attn_dumb(const bf16* __restrict__ qkv,
                                                 const int* __restrict__ mask,
                                                 bf16* __restrict__ ao) {
  int id = blockIdx.x;
  int qt = id % 36, h = (id / 36) & 3, b = id / 144;
  int tid = threadIdx.x, qq = tid & 63, pp = tid >> 6;
  int q0 = qt * 64;
  const size_t HSZ = (size_t)N_N * 64;
  const bf16* Qb = qkv + ((size_t)b * N_H + h) * HSZ;
  const bf16* Kb = qkv + ((size_t)N_B * N_H + (size_t)b * N_H + h) * HSZ;
  const bf16* Vb = qkv + ((size_t)2 * N_B * N_H + (size_t)b * N_H + h) * HSZ;
  const int* mb = mask + b * N_N;

  __shared__ float P[64][65];
  __shared__ float m_run[64], s_run[64], alpha_l[64], red[4][64];
  if (tid < 64) { m_run[tid] = -3.0e38f; s_run[tid] = 0.f; }
  __syncthreads();

  float qreg[64];
  const bf16* Qp = Qb + (size_t)(q0 + qq) * 64;
#pragma unroll
  for (int d = 0; d < 64; ++d) qreg[d] = __bfloat162float(Qp[d]);
  float acc[16];
#pragma unroll
  for (int i = 0; i < 16; ++i) acc[i] = 0.f;

  for (int kb = 0; kb < N_N; kb += 64) {
    float sv[16];
    int valid[16];
    float lmax = -3.0e38f;
#pragma unroll
    for (int i = 0; i < 16; ++i) {
      int k = kb + pp * 16 + i;
      valid[i] = mb[k];
      const bf16* Kp = Kb + (size_t)k * 64;
      float s = 0.f;
#pragma unroll
      for (int d = 0; d < 64; ++d) s += qreg[d] * __bfloat162float(Kp[d]);
      sv[i] = s;
      if (valid[i]) lmax = fmaxf(lmax, s);
    }
    red[pp][qq] = lmax;
    __syncthreads();
    if (pp == 0) {
      float mnew = fmaxf(fmaxf(m_run[qq], red[0][qq]),
                         fmaxf(red[1][qq], fmaxf(red[2][qq], red[3][qq])));
      alpha_l[qq] = expf(m_run[qq] - mnew);
      m_run[qq] = mnew;
    }
    __syncthreads();
    {
      float mnew = m_run[qq];
      float psum = 0.f;
#pragma unroll
      for (int i = 0; i < 16; ++i) {
        float p = valid[i] ? expf(sv[i] - mnew) : 0.f;
        psum += p;
        P[qq][pp * 16 + i] = p;
      }
      red[pp][qq] = psum;
    }
    __syncthreads();
    if (pp == 0) {
      s_run[qq] = s_run[qq] * alpha_l[qq] +
                  ((red[0][qq] + red[1][qq]) + (red[2][qq] + red[3][qq]));
    }
    float al = alpha_l[qq];
#pragma unroll
    for (int i = 0; i < 16; ++i) acc[i] *= al;
    for (int k = 0; k < 64; ++k) {
      float p = P[qq][k];
      const bf16* Vp = Vb + (size_t)(kb + k) * 64 + pp * 16;
#pragma unroll
      for (int i = 0; i < 16; ++i) acc[i] += p * __bfloat162float(Vp[i]);
    }
    __syncthreads();
  }
  float sr = s_run[qq];
  float inv = (sr > 0.f) ? (1.f / sr) : 0.f;
  bf16* Op = ao + ((size_t)b * N_N + q0 + qq) * 256 + h * 64 + pp * 16;
#pragma unroll
  for (int i = 0; i < 16; ++i) Op[i] = __float2bfloat16(acc[i] * inv);
}

// ---------------- dumb proj: scalar fp32 + bias + residual ------------------
__global__ __launch_bounds__(256) void proj_dumb(const float* __restrict__ wproj,
                                                 const bf16* __restrict__ ao,
                                                 const float* __restrict__ bproj,
                                                 const float* __restrict__ x,
                                                 float* __restrict__ out) {
  int id = blockIdx.x;               // 2048 = 8 * 256
  int b = id / 256, o = id % 256;
  __shared__ float wl[256];
  wl[threadIdx.x] = wproj[(size_t)o * 256 + threadIdx.x];
  __syncthreads();
  float bo = bproj[o];
#pragma unroll 1
  for (int t = 0; t < 9; ++t) {
    int n = threadIdx.x + t * 256;
    const bf16* ap = ao + ((size_t)b * N_N + n) * 256;
    float s = 0.f;
    for (int c = 0; c < 256; ++c) s += wl[c] * __bfloat162float(ap[c]);
    size_t idx = ((size_t)b * 256 + o) * N_N + n;
    out[idx] = s + bo + x[idx];
  }
}

// ---------------- host launch ------------------------------------------------
extern "C" void kernel_launch(void* const* d_in, const int* in_sizes, int n_in,
                              void* d_out, int out_size, void* d_ws, size_t ws_size,
                              hipStream_t stream) {
  (void)in_sizes; (void)n_in; (void)out_size; (void)ws_size;
  const float* x     = (const float*)d_in[0];
  const int*   mask  = (const int*)d_in[1];
  const float* gnw   = (const float*)d_in[2];
  const float* gnb   = (const float*)d_in[3];
  const float* wqkv  = (const float*)d_in[4];
  const float* wproj = (const float*)d_in[5];
  const float* bproj = (const float*)d_in[6];
  float* out = (float*)d_out;
  char* ws = (char*)d_ws;

  float* mr  = (float*)(ws + 0);            // 64 B
  bf16* xn   = (bf16*)(ws + 4096);          // 9,437,184 B  (aliased as ao later)
  bf16* qkv  = (bf16*)(ws + 4096 + 9437184);// 28,311,552 B; total ~37.75 MB
  bf16* ao   = xn;  // xn dead after qkv_dumb; attn does not read xn

  stats_dumb<<<8, 256, 0, stream>>>(x, mr);
  gn_apply<<<4608, 256, 0, stream>>>(x, mr, gnw, gnb, xn);
  qkv_dumb<<<6144, 256, 0, stream>>>(wqkv, xn, qkv);
  attn_dumb<<<1152, 256, 0, stream>>>(qkv, mask, ao);
  proj_dumb<<<2048, 256, 0, stream>>>(wproj, ao, bproj, x, out);
}

// Round 6
// 1564.965 us; speedup vs baseline: 2.8254x; 2.8254x over previous
//
#include <hip/hip_runtime.h>
#include <hip/hip_bf16.h>

typedef __hip_bfloat16 bf16;
typedef short bf16x4 __attribute__((ext_vector_type(4)));
typedef short bf16x8 __attribute__((ext_vector_type(8)));
typedef float f32x4 __attribute__((ext_vector_type(4)));

#define N_B 8
#define N_C 256
#define N_H 4
#define N_N 2304
#define N_ELEM 589824   // N_C * N_N

static __device__ __forceinline__ f32x4 mfma32(bf16x8 a, bf16x8 b, f32x4 c) {
  return __builtin_amdgcn_mfma_f32_16x16x32_bf16(a, b, c, 0, 0, 0);
}

// ---------------- per-batch mean/rstd, one block per batch ------------------
__global__ __launch_bounds__(256) void stats_dumb(const float* __restrict__ x,
                                                  float* __restrict__ mr) {
  int b = blockIdx.x;
  const float* xb = x + (size_t)b * N_ELEM;
  float s = 0.f, ss = 0.f;
  for (int i = threadIdx.x; i < N_ELEM; i += 256) {
    float v = xb[i];
    s += v; ss += v * v;
  }
  __shared__ float ls[256], lss[256];
  ls[threadIdx.x] = s; lss[threadIdx.x] = ss;
  __syncthreads();
  for (int off = 128; off; off >>= 1) {
    if (threadIdx.x < off) {
      ls[threadIdx.x]  += ls[threadIdx.x + off];
      lss[threadIdx.x] += lss[threadIdx.x + off];
    }
    __syncthreads();
  }
  if (threadIdx.x == 0) {
    float mean = ls[0] * (1.f / (float)N_ELEM);
    float var  = lss[0] * (1.f / (float)N_ELEM) - mean * mean;
    mr[b * 2]     = mean;
    mr[b * 2 + 1] = rsqrtf(var + 1e-5f);
  }
}

// ---------------- materialize xn[b][c][n] (bf16 for footprint only) ---------
__global__ __launch_bounds__(256) void gn_apply(const float* __restrict__ x,
                                                const float* __restrict__ mr,
                                                const float* __restrict__ gnw,
                                                const float* __restrict__ gnb,
                                                bf16* __restrict__ xn) {
  int blk = blockIdx.x;              // 4608 = 8 * 576
  int b = blk / 576, rem = blk % 576;
  float mean = mr[b * 2], rstd = mr[b * 2 + 1];
  int e0 = rem * 1024 + threadIdx.x * 4;   // 4-aligned; 2304 % 4 == 0 so same c
  int c = e0 / N_N;
  float a  = rstd * gnw[c];
  float dd = gnb[c] - mean * a;
  const float* xp = x + (size_t)b * N_ELEM + e0;
  bf16* xo = xn + (size_t)b * N_ELEM + e0;
#pragma unroll
  for (int j = 0; j < 4; ++j) xo[j] = __float2bfloat16(xp[j] * a + dd);
}

// ---------------- dumb QKV: scalar fp32 dots, direct indexing ---------------
// Q,K -> [seg][b][h][n][64] (q pre-scaled 0.125); V -> V^T [b][h][d][N_N]
__global__ __launch_bounds__(256) void qkv_dumb(const float* __restrict__ wqkv,
                                                const bf16* __restrict__ xn,
                                                bf16* __restrict__ qkv) {
  int id = blockIdx.x;               // 6144 = 8 * 768
  int b = id / 768, o = id % 768;
  const float* wr = wqkv + (size_t)o * 256;
  const bf16* xb = xn + (size_t)b * N_ELEM;
  __shared__ float wl[256];
  wl[threadIdx.x] = wr[threadIdx.x];
  __syncthreads();
  float s[9];
#pragma unroll
  for (int t = 0; t < 9; ++t) s[t] = 0.f;
  for (int c = 0; c < 256; ++c) {
    float w = wl[c];
    const bf16* xc = xb + (size_t)c * N_N;
#pragma unroll
    for (int t = 0; t < 9; ++t) {
      int n = threadIdx.x + t * 256;
      s[t] += w * __bfloat162float(xc[n]);
    }
  }
  int seg = o >> 8, h = (o >> 6) & 3, d = o & 63;
  bf16* Base = qkv + ((size_t)seg * N_B * N_H + (size_t)b * N_H + h) * (size_t)N_N * 64;
  if (seg < 2) {
    float sc = (seg == 0) ? 0.125f : 1.0f;
#pragma unroll
    for (int t = 0; t < 9; ++t) {
      int n = threadIdx.x + t * 256;
      Base[(size_t)n * 64 + d] = __float2bfloat16(s[t] * sc);
    }
  } else {  // V transposed: vt[d][n], coalesced (d fixed per block)
#pragma unroll
    for (int t = 0; t < 9; ++t) {
      int n = threadIdx.x + t * 256;
      Base[(size_t)d * N_N + n] = __float2bfloat16(s[t]);
    }
  }
}

// ---------------- MFMA flash attention (verified m97 pattern) ---------------
// Per (b,h,64-q tile), loop 64-key tiles:
//   S-GEMM: A=K rows, B=Q rows (both k-contig) -> LDS fp32 S[key][q]
//   scalar softmax identical to the PASSING R5 code (expf, mask direct)
//   PV: A=V^T rows d (k=key contig), B=P rows q (LDS bf16) -> acc^T
__global__ __launch_bounds__(256) void attn_mfma(const bf16* __restrict__ qkv,
                                                 const int* __restrict__ mask,
                                                 bf16* __restrict__ ao) {
  int id = blockIdx.x;
  int qt = id % 36, h = (id / 36) & 3, b = id / 144;
  int tid = threadIdx.x;
  int lane = tid & 63, wave = tid >> 6;
  int l15 = lane & 15, g = lane >> 4, g8 = g * 8;
  int q0 = qt * 64;
  const size_t HSZ = (size_t)N_N * 64;
  const bf16* Qb = qkv + ((size_t)b * N_H + h) * HSZ;
  const bf16* Kb = qkv + ((size_t)(N_B * N_H) + (size_t)b * N_H + h) * HSZ;
  const bf16* Vt = qkv + ((size_t)(2 * N_B * N_H) + (size_t)b * N_H + h) * HSZ;
  const int* mb = mask + b * N_N;

  __shared__ float S[64][68];
  __shared__ bf16 P[64][64];
  __shared__ float m_run[64], s_run[64], alpha_l[64], red[4][64];
  if (tid < 64) { m_run[tid] = -3.0e38f; s_run[tid] = 0.f; }
  __syncthreads();

  // Q fragments (loop-invariant): B-operand rows q0+qsub*16+l15
  bf16x8 qf[4][2];
#pragma unroll
  for (int qsub = 0; qsub < 4; ++qsub) {
    const bf16* Qp = Qb + (size_t)(q0 + qsub * 16 + l15) * 64;
    qf[qsub][0] = *(const bf16x8*)(Qp + g8);
    qf[qsub][1] = *(const bf16x8*)(Qp + 32 + g8);
  }
  f32x4 z = {0.f, 0.f, 0.f, 0.f};
  f32x4 acc[4];   // acc[qsub]: d = wave*16+g*4+r, q = q0+qsub*16+l15
#pragma unroll
  for (int i = 0; i < 4; ++i) acc[i] = z;
  int qq = tid & 63, pp = tid >> 6;

  for (int kb = 0; kb < N_N; kb += 64) {
    // ---- S-GEMM: this wave computes keys kb+wave*16 .. +15
    {
      const bf16* Kp = Kb + (size_t)(kb + wave * 16 + l15) * 64;
      bf16x8 kf0 = *(const bf16x8*)(Kp + g8);
      bf16x8 kf1 = *(const bf16x8*)(Kp + 32 + g8);
#pragma unroll
      for (int qsub = 0; qsub < 4; ++qsub) {
        f32x4 s = z;
        s = mfma32(kf0, qf[qsub][0], s);
        s = mfma32(kf1, qf[qsub][1], s);
#pragma unroll
        for (int r = 0; r < 4; ++r)
          S[wave * 16 + g * 4 + r][qsub * 16 + l15] = s[r];
      }
    }
    __syncthreads();
    // ---- softmax (identical structure to passing R5 scalar code)
    float sv[16];
    int valid[16];
    float lmax = -3.0e38f;
#pragma unroll
    for (int i = 0; i < 16; ++i) {
      int k = pp * 16 + i;
      valid[i] = mb[kb + k];
      sv[i] = S[k][qq];
      if (valid[i]) lmax = fmaxf(lmax, sv[i]);
    }
    red[pp][qq] = lmax;
    __syncthreads();
    if (pp == 0) {
      float mnew = fmaxf(fmaxf(m_run[qq], red[0][qq]),
                         fmaxf(red[1][qq], fmaxf(red[2][qq], red[3][qq])));
      alpha_l[qq] = expf(m_run[qq] - mnew);
      m_run[qq] = mnew;
    }
    __syncthreads();
    {
      float mnew = m_run[qq];
      float psum = 0.f;
#pragma unroll
      for (int i = 0; i < 16; ++i) {
        float p = valid[i] ? expf(sv[i] - mnew) : 0.f;
        psum += p;
        P[qq][pp * 16 + i] = __float2bfloat16(p);
      }
      red[pp][qq] = psum;
    }
    __syncthreads();
    if (pp == 0) {
      s_run[qq] = s_run[qq] * alpha_l[qq] +
                  ((red[0][qq] + red[1][qq]) + (red[2][qq] + red[3][qq]));
    }
    // ---- PV: A = V^T rows d (k=key contig), B = P rows q
    {
      const bf16* Vp = Vt + (size_t)(wave * 16 + l15) * N_N + kb;
      bf16x8 vf0 = *(const bf16x8*)(Vp + g8);
      bf16x8 vf1 = *(const bf16x8*)(Vp + 32 + g8);
#pragma unroll
      for (int qsub = 0; qsub < 4; ++qsub) {
        float al = alpha_l[qsub * 16 + l15];
        acc[qsub][0] *= al; acc[qsub][1] *= al;
        acc[qsub][2] *= al; acc[qsub][3] *= al;
        bf16x8 pf0 = *(const bf16x8*)(&P[qsub * 16 + l15][g8]);
        bf16x8 pf1 = *(const bf16x8*)(&P[qsub * 16 + l15][32 + g8]);
        acc[qsub] = mfma32(vf0, pf0, acc[qsub]);
        acc[qsub] = mfma32(vf1, pf1, acc[qsub]);
      }
    }
    __syncthreads();
  }
  // ---- epilogue: normalize, store ao[b][n][c], c = h*64 + d
#pragma unroll
  for (int qsub = 0; qsub < 4; ++qsub) {
    float sr = s_run[qsub * 16 + l15];
    float inv = (sr > 0.f) ? (1.f / sr) : 0.f;
    union { bf16x4 v; struct { bf16 a, b, c, d; } s; } pk;
    pk.s.a = __float2bfloat16(acc[qsub][0] * inv);
    pk.s.b = __float2bfloat16(acc[qsub][1] * inv);
    pk.s.c = __float2bfloat16(acc[qsub][2] * inv);
    pk.s.d = __float2bfloat16(acc[qsub][3] * inv);
    bf16* Op = ao + ((size_t)b * N_N + q0 + qsub * 16 + l15) * 256 +
               h * 64 + wave * 16 + g * 4;
    *reinterpret_cast<bf16x4*>(Op) = pk.v;
  }
}

// ---------------- dumb proj: scalar fp32 + bias + residual ------------------
__global__ __launch_bounds__(256) void proj_dumb(const float* __restrict__ wproj,
                                                 const bf16* __restrict__ ao,
                                                 const float* __restrict__ bproj,
                                                 const float* __restrict__ x,
                                                 float* __restrict__ out) {
  int id = blockIdx.x;               // 2048 = 8 * 256
  int b = id / 256, o = id % 256;
  __shared__ float wl[256];
  wl[threadIdx.x] = wproj[(size_t)o * 256 + threadIdx.x];
  __syncthreads();
  float bo = bproj[o];
#pragma unroll 1
  for (int t = 0; t < 9; ++t) {
    int n = threadIdx.x + t * 256;
    const bf16* ap = ao + ((size_t)b * N_N + n) * 256;
    float s = 0.f;
    for (int c = 0; c < 256; ++c) s += wl[c] * __bfloat162float(ap[c]);
    size_t idx = ((size_t)b * 256 + o) * N_N + n;
    out[idx] = s + bo + x[idx];
  }
}

// ---------------- host launch ------------------------------------------------
extern "C" void kernel_launch(void* const* d_in, const int* in_sizes, int n_in,
                              void* d_out, int out_size, void* d_ws, size_t ws_size,
                              hipStream_t stream) {
  (void)in_sizes; (void)n_in; (void)out_size; (void)ws_size;
  const float* x     = (const float*)d_in[0];
  const int*   mask  = (const int*)d_in[1];
  const float* gnw   = (const float*)d_in[2];
  const float* gnb   = (const float*)d_in[3];
  const float* wqkv  = (const float*)d_in[4];
  const float* wproj = (const float*)d_in[5];
  const float* bproj = (const float*)d_in[6];
  float* out = (float*)d_out;
  char* ws = (char*)d_ws;

  float* mr  = (float*)(ws + 0);             // 64 B
  bf16* xn   = (bf16*)(ws + 4096);           // 9,437,184 B (aliased as ao later)
  bf16* qkv  = (bf16*)(ws + 4096 + 9437184); // 28,311,552 B; total ~37.75 MB
  bf16* ao   = xn;  // xn dead after qkv_dumb; attn does not read xn

  stats_dumb<<<8, 256, 0, stream>>>(x, mr);
  gn_apply<<<4608, 256, 0, stream>>>(x, mr, gnw, gnb, xn);
  qkv_dumb<<<6144, 256, 0, stream>>>(wqkv, xn, qkv);
  attn_mfma<<<1152, 256, 0, stream>>>(qkv, mask, ao);
  proj_dumb<<<2048, 256, 0, stream>>>(wproj, ao, bproj, x, out);
}

// Round 7
// 673.312 us; speedup vs baseline: 6.5671x; 2.3243x over previous
//
#include <hip/hip_runtime.h>
#include <hip/hip_bf16.h>

typedef __hip_bfloat16 bf16;
typedef short bf16x4 __attribute__((ext_vector_type(4)));
typedef short bf16x8 __attribute__((ext_vector_type(8)));
typedef float f32x4 __attribute__((ext_vector_type(4)));

#define N_B 8
#define N_C 256
#define N_H 4
#define N_N 2304
#define N_ELEM 589824   // N_C * N_N

static __device__ __forceinline__ f32x4 mfma32(bf16x8 a, bf16x8 b, f32x4 c) {
  return __builtin_amdgcn_mfma_f32_16x16x32_bf16(a, b, c, 0, 0, 0);
}

// ---------------- GN stats: partial sums per (batch, chunk) -----------------
__global__ __launch_bounds__(256) void gn_stats(const float* __restrict__ x,
                                                float* __restrict__ part) {
  int b = blockIdx.x >> 5, chunk = blockIdx.x & 31;
  const f32x4* p = (const f32x4*)(x + (size_t)b * N_ELEM + (size_t)chunk * 18432);
  float s = 0.f, ss = 0.f;
  for (int i = threadIdx.x; i < 4608; i += 256) {
    f32x4 v = p[i];
    s  += (v[0] + v[1]) + (v[2] + v[3]);
    ss += (v[0] * v[0] + v[1] * v[1]) + (v[2] * v[2] + v[3] * v[3]);
  }
  for (int off = 32; off; off >>= 1) {
    s  += __shfl_xor(s, off);
    ss += __shfl_xor(ss, off);
  }
  __shared__ float ls[8];
  int wv = threadIdx.x >> 6;
  if ((threadIdx.x & 63) == 0) { ls[wv] = s; ls[4 + wv] = ss; }
  __syncthreads();
  if (threadIdx.x == 0) {
    part[blockIdx.x * 2]     = ls[0] + ls[1] + ls[2] + ls[3];
    part[blockIdx.x * 2 + 1] = ls[4] + ls[5] + ls[6] + ls[7];
  }
}

__global__ void stats_final(const float* __restrict__ part, float* __restrict__ mr) {
  int b = threadIdx.x;
  if (b < N_B) {
    float s = 0.f, ss = 0.f;
    for (int i = 0; i < 32; ++i) {
      s  += part[b * 64 + i * 2];
      ss += part[b * 64 + i * 2 + 1];
    }
    float mean = s * (1.f / (float)N_ELEM);
    float var  = ss * (1.f / (float)N_ELEM) - mean * mean;
    mr[b * 2]     = mean;
    mr[b * 2 + 1] = rsqrtf(var + 1e-5f);
  }
}

// ---------------- materialize xn[b][c][n] (bf16) ----------------------------
__global__ __launch_bounds__(256) void gn_apply(const float* __restrict__ x,
                                                const float* __restrict__ mr,
                                                const float* __restrict__ gnw,
                                                const float* __restrict__ gnb,
                                                bf16* __restrict__ xn) {
  int blk = blockIdx.x;              // 4608 = 8 * 576
  int b = blk / 576, rem = blk % 576;
  float mean = mr[b * 2], rstd = mr[b * 2 + 1];
  int e0 = rem * 1024 + threadIdx.x * 4;   // 4-aligned; 2304 % 4 == 0 so same c
  int c = e0 / N_N;
  float a  = rstd * gnw[c];
  float dd = gnb[c] - mean * a;
  const float* xp = x + (size_t)b * N_ELEM + e0;
  bf16* xo = xn + (size_t)b * N_ELEM + e0;
#pragma unroll
  for (int j = 0; j < 4; ++j) xo[j] = __float2bfloat16(xp[j] * a + dd);
}

// ---------------- wproj fp32 -> bf16 -----------------------------------------
__global__ __launch_bounds__(256) void wp_conv(const float* __restrict__ wp,
                                               bf16* __restrict__ wpb) {
  int i = blockIdx.x * 256 + threadIdx.x;
  wpb[i] = __float2bfloat16(wp[i]);
}

// ---------------- dumb QKV: scalar fp32 dots, direct indexing ---------------
// Q,K -> [seg][b][h][n][64] (q pre-scaled 0.125); V -> V^T [b][h][d][N_N]
__global__ __launch_bounds__(256) void qkv_dumb(const float* __restrict__ wqkv,
                                                const bf16* __restrict__ xn,
                                                bf16* __restrict__ qkv) {
  int id = blockIdx.x;               // 6144 = 8 * 768
  int b = id / 768, o = id % 768;
  const float* wr = wqkv + (size_t)o * 256;
  const bf16* xb = xn + (size_t)b * N_ELEM;
  __shared__ float wl[256];
  wl[threadIdx.x] = wr[threadIdx.x];
  __syncthreads();
  float s[9];
#pragma unroll
  for (int t = 0; t < 9; ++t) s[t] = 0.f;
  for (int c = 0; c < 256; ++c) {
    float w = wl[c];
    const bf16* xc = xb + (size_t)c * N_N;
#pragma unroll
    for (int t = 0; t < 9; ++t) {
      int n = threadIdx.x + t * 256;
      s[t] += w * __bfloat162float(xc[n]);
    }
  }
  int seg = o >> 8, h = (o >> 6) & 3, d = o & 63;
  bf16* Base = qkv + ((size_t)seg * N_B * N_H + (size_t)b * N_H + h) * (size_t)N_N * 64;
  if (seg < 2) {
    float sc = (seg == 0) ? 0.125f : 1.0f;
#pragma unroll
    for (int t = 0; t < 9; ++t) {
      int n = threadIdx.x + t * 256;
      Base[(size_t)n * 64 + d] = __float2bfloat16(s[t] * sc);
    }
  } else {  // V transposed: vt[d][n], coalesced (d fixed per block)
#pragma unroll
    for (int t = 0; t < 9; ++t) {
      int n = threadIdx.x + t * 256;
      Base[(size_t)d * N_N + n] = __float2bfloat16(s[t]);
    }
  }
}

// ---------------- MFMA flash attention (verified m97 pattern) ---------------
__global__ __launch_bounds__(256) void attn_mfma(const bf16* __restrict__ qkv,
                                                 const int* __restrict__ mask,
                                                 bf16* __restrict__ ao) {
  int id = blockIdx.x;
  int qt = id % 36, h = (id / 36) & 3, b = id / 144;
  int tid = threadIdx.x;
  int lane = tid & 63, wave = tid >> 6;
  int l15 = lane & 15, g = lane >> 4, g8 = g * 8;
  int q0 = qt * 64;
  const size_t HSZ = (size_t)N_N * 64;
  const bf16* Qb = qkv + ((size_t)b * N_H + h) * HSZ;
  const bf16* Kb = qkv + ((size_t)(N_B * N_H) + (size_t)b * N_H + h) * HSZ;
  const bf16* Vt = qkv + ((size_t)(2 * N_B * N_H) + (size_t)b * N_H + h) * HSZ;
  const int* mb = mask + b * N_N;

  __shared__ float S[64][68];
  __shared__ bf16 P[64][64];
  __shared__ float m_run[64], s_run[64], alpha_l[64], red[4][64];
  if (tid < 64) { m_run[tid] = -3.0e38f; s_run[tid] = 0.f; }
  __syncthreads();

  bf16x8 qf[4][2];
#pragma unroll
  for (int qsub = 0; qsub < 4; ++qsub) {
    const bf16* Qp = Qb + (size_t)(q0 + qsub * 16 + l15) * 64;
    qf[qsub][0] = *(const bf16x8*)(Qp + g8);
    qf[qsub][1] = *(const bf16x8*)(Qp + 32 + g8);
  }
  f32x4 z = {0.f, 0.f, 0.f, 0.f};
  f32x4 acc[4];
#pragma unroll
  for (int i = 0; i < 4; ++i) acc[i] = z;
  int qq = tid & 63, pp = tid >> 6;

  for (int kb = 0; kb < N_N; kb += 64) {
    {
      const bf16* Kp = Kb + (size_t)(kb + wave * 16 + l15) * 64;
      bf16x8 kf0 = *(const bf16x8*)(Kp + g8);
      bf16x8 kf1 = *(const bf16x8*)(Kp + 32 + g8);
#pragma unroll
      for (int qsub = 0; qsub < 4; ++qsub) {
        f32x4 s = z;
        s = mfma32(kf0, qf[qsub][0], s);
        s = mfma32(kf1, qf[qsub][1], s);
#pragma unroll
        for (int r = 0; r < 4; ++r)
          S[wave * 16 + g * 4 + r][qsub * 16 + l15] = s[r];
      }
    }
    __syncthreads();
    float sv[16];
    int valid[16];
    float lmax = -3.0e38f;
#pragma unroll
    for (int i = 0; i < 16; ++i) {
      int k = pp * 16 + i;
      valid[i] = mb[kb + k];
      sv[i] = S[k][qq];
      if (valid[i]) lmax = fmaxf(lmax, sv[i]);
    }
    red[pp][qq] = lmax;
    __syncthreads();
    if (pp == 0) {
      float mnew = fmaxf(fmaxf(m_run[qq], red[0][qq]),
                         fmaxf(red[1][qq], fmaxf(red[2][qq], red[3][qq])));
      alpha_l[qq] = expf(m_run[qq] - mnew);
      m_run[qq] = mnew;
    }
    __syncthreads();
    {
      float mnew = m_run[qq];
      float psum = 0.f;
#pragma unroll
      for (int i = 0; i < 16; ++i) {
        float p = valid[i] ? expf(sv[i] - mnew) : 0.f;
        psum += p;
        P[qq][pp * 16 + i] = __float2bfloat16(p);
      }
      red[pp][qq] = psum;
    }
    __syncthreads();
    if (pp == 0) {
      s_run[qq] = s_run[qq] * alpha_l[qq] +
                  ((red[0][qq] + red[1][qq]) + (red[2][qq] + red[3][qq]));
    }
    {
      const bf16* Vp = Vt + (size_t)(wave * 16 + l15) * N_N + kb;
      bf16x8 vf0 = *(const bf16x8*)(Vp + g8);
      bf16x8 vf1 = *(const bf16x8*)(Vp + 32 + g8);
#pragma unroll
      for (int qsub = 0; qsub < 4; ++qsub) {
        float al = alpha_l[qsub * 16 + l15];
        acc[qsub][0] *= al; acc[qsub][1] *= al;
        acc[qsub][2] *= al; acc[qsub][3] *= al;
        bf16x8 pf0 = *(const bf16x8*)(&P[qsub * 16 + l15][g8]);
        bf16x8 pf1 = *(const bf16x8*)(&P[qsub * 16 + l15][32 + g8]);
        acc[qsub] = mfma32(vf0, pf0, acc[qsub]);
        acc[qsub] = mfma32(vf1, pf1, acc[qsub]);
      }
    }
    __syncthreads();
  }
#pragma unroll
  for (int qsub = 0; qsub < 4; ++qsub) {
    float sr = s_run[qsub * 16 + l15];
    float inv = (sr > 0.f) ? (1.f / sr) : 0.f;
    union { bf16x4 v; struct { bf16 a, b, c, d; } s; } pk;
    pk.s.a = __float2bfloat16(acc[qsub][0] * inv);
    pk.s.b = __float2bfloat16(acc[qsub][1] * inv);
    pk.s.c = __float2bfloat16(acc[qsub][2] * inv);
    pk.s.d = __float2bfloat16(acc[qsub][3] * inv);
    bf16* Op = ao + ((size_t)b * N_N + q0 + qsub * 16 + l15) * 256 +
               h * 64 + wave * 16 + g * 4;
    *reinterpret_cast<bf16x4*>(Op) = pk.v;
  }
}

// ---------------- proj GEMM (MFMA) + bias + residual, fp32 out --------------
// C[o][n] = sum_c W[o][c]*ao[n][c]; A=W rows (k=c contig), B=ao rows (k=c contig)
__global__ __launch_bounds__(256) void proj_gemm(const bf16* __restrict__ wpb,
                                                 const bf16* __restrict__ ao,
                                                 const float* __restrict__ bproj,
                                                 const float* __restrict__ x,
                                                 float* __restrict__ out) {
  int id = blockIdx.x;               // 576 = 18nt * 4ot * 8b
  int nt = id % 18, ot = (id / 18) & 3, b = id / 72;
  int o0 = ot * 64, n0 = nt * 128;
  int lane = threadIdx.x & 63, wave = threadIdx.x >> 6;
  int l15 = lane & 15, g = lane >> 4, g8 = g * 8;
  const bf16* Ab = wpb + (size_t)(o0 + l15) * 256 + g8;
  const bf16* Bb = ao + ((size_t)b * N_N + n0 + wave * 32 + l15) * 256 + g8;
  f32x4 z = {0.f, 0.f, 0.f, 0.f};
  f32x4 acc[4][2];
#pragma unroll
  for (int i = 0; i < 4; ++i) { acc[i][0] = z; acc[i][1] = z; }
#pragma unroll
  for (int kk = 0; kk < 8; ++kk) {
    int co = kk * 32;
    bf16x8 b0 = *(const bf16x8*)(Bb + co);
    bf16x8 b1 = *(const bf16x8*)(Bb + 16 * 256 + co);
#pragma unroll
    for (int mb = 0; mb < 4; ++mb) {
      bf16x8 aa = *(const bf16x8*)(Ab + mb * 4096 + co);
      acc[mb][0] = mfma32(aa, b0, acc[mb][0]);
      acc[mb][1] = mfma32(aa, b1, acc[mb][1]);
    }
  }
  int jb = n0 + wave * 32;
#pragma unroll
  for (int mb = 0; mb < 4; ++mb) {
    int ob = o0 + mb * 16 + g * 4;
    f32x4 bp = *(const f32x4*)(bproj + ob);
#pragma unroll
    for (int nb = 0; nb < 2; ++nb) {
      int n = jb + nb * 16 + l15;
#pragma unroll
      for (int r = 0; r < 4; ++r) {
        size_t idx = ((size_t)b * 256 + ob + r) * N_N + n;
        out[idx] = acc[mb][nb][r] + bp[r] + x[idx];
      }
    }
  }
}

// ---------------- host launch ------------------------------------------------
extern "C" void kernel_launch(void* const* d_in, const int* in_sizes, int n_in,
                              void* d_out, int out_size, void* d_ws, size_t ws_size,
                              hipStream_t stream) {
  (void)in_sizes; (void)n_in; (void)out_size; (void)ws_size;
  const float* x     = (const float*)d_in[0];
  const int*   mask  = (const int*)d_in[1];
  const float* gnw   = (const float*)d_in[2];
  const float* gnb   = (const float*)d_in[3];
  const float* wqkv  = (const float*)d_in[4];
  const float* wproj = (const float*)d_in[5];
  const float* bproj = (const float*)d_in[6];
  float* out = (float*)d_out;
  char* ws = (char*)d_ws;

  float* part = (float*)(ws + 0);                 // 2048 B
  float* mr   = (float*)(ws + 2048);              // 64 B
  bf16*  wpb  = (bf16*)(ws + 4096);               // 131072 B
  bf16*  xn   = (bf16*)(ws + 4096 + 131072);      // 9,437,184 B (reused as ao)
  bf16*  qkv  = (bf16*)(ws + 4096 + 131072 + 9437184); // 28,311,552 B
  bf16*  ao   = xn;  // xn dead after qkv_dumb

  gn_stats<<<256, 256, 0, stream>>>(x, part);
  stats_final<<<1, 64, 0, stream>>>(part, mr);
  gn_apply<<<4608, 256, 0, stream>>>(x, mr, gnw, gnb, xn);
  wp_conv<<<256, 256, 0, stream>>>(wproj, wpb);
  qkv_dumb<<<6144, 256, 0, stream>>>(wqkv, xn, qkv);
  attn_mfma<<<1152, 256, 0, stream>>>(qkv, mask, ao);
  proj_gemm<<<576, 256, 0, stream>>>(wpb, ao, bproj, x, out);
}

// Round 8
// 312.009 us; speedup vs baseline: 14.1717x; 2.1580x over previous
//
#include <hip/hip_runtime.h>
#include <hip/hip_bf16.h>

typedef __hip_bfloat16 bf16;
typedef short bf16x4 __attribute__((ext_vector_type(4)));
typedef short bf16x8 __attribute__((ext_vector_type(8)));
typedef float f32x4 __attribute__((ext_vector_type(4)));

#define N_B 8
#define N_C 256
#define N_H 4
#define N_N 2304
#define N_ELEM 589824   // N_C * N_N

static __device__ __forceinline__ f32x4 mfma32(bf16x8 a, bf16x8 b, f32x4 c) {
  return __builtin_amdgcn_mfma_f32_16x16x32_bf16(a, b, c, 0, 0, 0);
}
static __device__ __forceinline__ short bfs(float f) {
  union { __hip_bfloat16 h; short s; } u;
  u.h = __float2bfloat16(f);
  return u.s;
}

// ---------------- GN stats: partial sums per (batch, chunk) -----------------
__global__ __launch_bounds__(256) void gn_stats(const float* __restrict__ x,
                                                float* __restrict__ part) {
  int b = blockIdx.x >> 5, chunk = blockIdx.x & 31;
  const f32x4* p = (const f32x4*)(x + (size_t)b * N_ELEM + (size_t)chunk * 18432);
  float s = 0.f, ss = 0.f;
  for (int i = threadIdx.x; i < 4608; i += 256) {
    f32x4 v = p[i];
    s  += (v[0] + v[1]) + (v[2] + v[3]);
    ss += (v[0] * v[0] + v[1] * v[1]) + (v[2] * v[2] + v[3] * v[3]);
  }
  for (int off = 32; off; off >>= 1) {
    s  += __shfl_xor(s, off);
    ss += __shfl_xor(ss, off);
  }
  __shared__ float ls[8];
  int wv = threadIdx.x >> 6;
  if ((threadIdx.x & 63) == 0) { ls[wv] = s; ls[4 + wv] = ss; }
  __syncthreads();
  if (threadIdx.x == 0) {
    part[blockIdx.x * 2]     = ls[0] + ls[1] + ls[2] + ls[3];
    part[blockIdx.x * 2 + 1] = ls[4] + ls[5] + ls[6] + ls[7];
  }
}

__global__ void stats_final(const float* __restrict__ part, float* __restrict__ mr) {
  int b = threadIdx.x;
  if (b < N_B) {
    float s = 0.f, ss = 0.f;
    for (int i = 0; i < 32; ++i) {
      s  += part[b * 64 + i * 2];
      ss += part[b * 64 + i * 2 + 1];
    }
    float mean = s * (1.f / (float)N_ELEM);
    float var  = ss * (1.f / (float)N_ELEM) - mean * mean;
    mr[b * 2]     = mean;
    mr[b * 2 + 1] = rsqrtf(var + 1e-5f);
  }
}

// ---------------- weight converts -------------------------------------------
__global__ __launch_bounds__(256) void wq_conv(const float* __restrict__ wq,
                                               bf16* __restrict__ wqb) {
  int i = blockIdx.x * 256 + threadIdx.x;   // 768 blocks -> 196608 elems
  int row = i >> 8;
  float sc = (row < 256) ? 0.125f : 1.0f;   // exact 2^-3 into Q rows
  wqb[i] = __float2bfloat16(wq[i] * sc);
}

__global__ __launch_bounds__(256) void wp_conv(const float* __restrict__ wp,
                                               bf16* __restrict__ wpb) {
  int i = blockIdx.x * 256 + threadIdx.x;
  wpb[i] = __float2bfloat16(wp[i]);
}

// ---------------- fused GN + transpose: x[b][c][n] f32 -> xt[b][n][c] bf16 --
__global__ __launch_bounds__(256) void xt_gn(const float* __restrict__ x,
                                             const float* __restrict__ mr,
                                             const float* __restrict__ gnw,
                                             const float* __restrict__ gnb,
                                             bf16* __restrict__ xt) {
  int id = blockIdx.x;               // 1152 = 36nt * 4ct * 8b
  int nt = id % 36, ct = (id / 36) & 3, b = id / 144;
  float mean = mr[b * 2], rstd = mr[b * 2 + 1];
  __shared__ bf16 tile[64][65];
  int tn = threadIdx.x & 63, tq = threadIdx.x >> 6;
  const float* xp = x + (size_t)b * N_ELEM + (size_t)(ct * 64) * N_N + nt * 64;
  for (int it = 0; it < 16; ++it) {
    int c = tq * 16 + it;
    int cg = ct * 64 + c;
    float a  = rstd * gnw[cg];
    float dd = gnb[cg] - mean * a;
    tile[c][tn] = __float2bfloat16(xp[(size_t)c * N_N + tn] * a + dd);
  }
  __syncthreads();
  // out (n = nt*64+nl, c = ct*64+tn) = tile[tn][nl]
  bf16* xo = xt + ((size_t)b * N_N + nt * 64) * 256 + ct * 64;
  for (int it = 0; it < 16; ++it) {
    int nl = tq * 16 + it;
    xo[(size_t)nl * 256 + tn] = tile[tn][nl];
  }
}

// ---------------- QKV GEMM (MFMA, clone of verified proj_gemm pattern) ------
// C[o][n] = sum_c Wq[o][c]*xt[n][c]; A=Wq rows, B=xt rows (both k=c contig).
// Q,K -> [seg][b][h][n][64]; V -> V^T [b][h][d][N_N].
__global__ __launch_bounds__(256) void qkv_mfma(const bf16* __restrict__ wqb,
                                                const bf16* __restrict__ xt,
                                                bf16* __restrict__ qkv) {
  int id = blockIdx.x;               // 1728 = 18nt * 12ot * 8b
  int nt = id % 18, ot = (id / 18) % 12, b = id / 216;
  int o0 = ot * 64, n0 = nt * 128;
  int lane = threadIdx.x & 63, wave = threadIdx.x >> 6;
  int l15 = lane & 15, g = lane >> 4, g8 = g * 8;
  const bf16* Ab = wqb + (size_t)(o0 + l15) * 256 + g8;
  const bf16* Bb = xt + ((size_t)b * N_N + n0 + wave * 32 + l15) * 256 + g8;
  f32x4 z = {0.f, 0.f, 0.f, 0.f};
  f32x4 acc[4][2];
#pragma unroll
  for (int i = 0; i < 4; ++i) { acc[i][0] = z; acc[i][1] = z; }
#pragma unroll
  for (int kk = 0; kk < 8; ++kk) {
    int co = kk * 32;
    bf16x8 b0 = *(const bf16x8*)(Bb + co);
    bf16x8 b1 = *(const bf16x8*)(Bb + 16 * 256 + co);
#pragma unroll
    for (int mb = 0; mb < 4; ++mb) {
      bf16x8 aa = *(const bf16x8*)(Ab + mb * 4096 + co);
      acc[mb][0] = mfma32(aa, b0, acc[mb][0]);
      acc[mb][1] = mfma32(aa, b1, acc[mb][1]);
    }
  }
  int seg = o0 >> 8, h = (o0 >> 6) & 3;
  int jb = n0 + wave * 32;
  bf16* Base = qkv + ((size_t)seg * (N_B * N_H) + (size_t)b * N_H + h) *
               ((size_t)N_N * 64);
  if (seg < 2) {
    // out[n][d]: n = jb+nb*16+l15, d = mb*16+g*4+r (4 contig -> bf16x4)
#pragma unroll
    for (int mb = 0; mb < 4; ++mb) {
#pragma unroll
      for (int nb = 0; nb < 2; ++nb) {
        int row = jb + nb * 16 + l15;
        int d0 = mb * 16 + g * 4;
        bf16x4 pk = {bfs(acc[mb][nb][0]), bfs(acc[mb][nb][1]),
                     bfs(acc[mb][nb][2]), bfs(acc[mb][nb][3])};
        *reinterpret_cast<bf16x4*>(Base + (size_t)row * 64 + d0) = pk;
      }
    }
  } else {
    // vt[d][n]: d = mb*16+g*4+r, n = jb+nb*16+l15
#pragma unroll
    for (int mb = 0; mb < 4; ++mb) {
#pragma unroll
      for (int nb = 0; nb < 2; ++nb) {
        int n = jb + nb * 16 + l15;
#pragma unroll
        for (int r = 0; r < 4; ++r) {
          int d = mb * 16 + g * 4 + r;
          Base[(size_t)d * N_N + n] = __float2bfloat16(acc[mb][nb][r]);
        }
      }
    }
  }
}

// ---------------- MFMA flash attention (verified) ---------------------------
__global__ __launch_bounds__(256) void attn_mfma(const bf16* __restrict__ qkv,
                                                 const int* __restrict__ mask,
                                                 bf16* __restrict__ ao) {
  int id = blockIdx.x;
  int qt = id % 36, h = (id / 36) & 3, b = id / 144;
  int tid = threadIdx.x;
  int lane = tid & 63, wave = tid >> 6;
  int l15 = lane & 15, g = lane >> 4, g8 = g * 8;
  int q0 = qt * 64;
  const size_t HSZ = (size_t)N_N * 64;
  const bf16* Qb = qkv + ((size_t)b * N_H + h) * HSZ;
  const bf16* Kb = qkv + ((size_t)(N_B * N_H) + (size_t)b * N_H + h) * HSZ;
  const bf16* Vt = qkv + ((size_t)(2 * N_B * N_H) + (size_t)b * N_H + h) * HSZ;
  const int* mb = mask + b * N_N;

  __shared__ float S[64][68];
  __shared__ bf16 P[64][64];
  __shared__ float m_run[64], s_run[64], alpha_l[64], red[4][64];
  if (tid < 64) { m_run[tid] = -3.0e38f; s_run[tid] = 0.f; }
  __syncthreads();

  bf16x8 qf[4][2];
#pragma unroll
  for (int qsub = 0; qsub < 4; ++qsub) {
    const bf16* Qp = Qb + (size_t)(q0 + qsub * 16 + l15) * 64;
    qf[qsub][0] = *(const bf16x8*)(Qp + g8);
    qf[qsub][1] = *(const bf16x8*)(Qp + 32 + g8);
  }
  f32x4 z = {0.f, 0.f, 0.f, 0.f};
  f32x4 acc[4];
#pragma unroll
  for (int i = 0; i < 4; ++i) acc[i] = z;
  int qq = tid & 63, pp = tid >> 6;

  for (int kb = 0; kb < N_N; kb += 64) {
    {
      const bf16* Kp = Kb + (size_t)(kb + wave * 16 + l15) * 64;
      bf16x8 kf0 = *(const bf16x8*)(Kp + g8);
      bf16x8 kf1 = *(const bf16x8*)(Kp + 32 + g8);
#pragma unroll
      for (int qsub = 0; qsub < 4; ++qsub) {
        f32x4 s = z;
        s = mfma32(kf0, qf[qsub][0], s);
        s = mfma32(kf1, qf[qsub][1], s);
#pragma unroll
        for (int r = 0; r < 4; ++r)
          S[wave * 16 + g * 4 + r][qsub * 16 + l15] = s[r];
      }
    }
    __syncthreads();
    float sv[16];
    int valid[16];
    float lmax = -3.0e38f;
#pragma unroll
    for (int i = 0; i < 16; ++i) {
      int k = pp * 16 + i;
      valid[i] = mb[kb + k];
      sv[i] = S[k][qq];
      if (valid[i]) lmax = fmaxf(lmax, sv[i]);
    }
    red[pp][qq] = lmax;
    __syncthreads();
    if (pp == 0) {
      float mnew = fmaxf(fmaxf(m_run[qq], red[0][qq]),
                         fmaxf(red[1][qq], fmaxf(red[2][qq], red[3][qq])));
      alpha_l[qq] = expf(m_run[qq] - mnew);
      m_run[qq] = mnew;
    }
    __syncthreads();
    {
      float mnew = m_run[qq];
      float psum = 0.f;
#pragma unroll
      for (int i = 0; i < 16; ++i) {
        float p = valid[i] ? expf(sv[i] - mnew) : 0.f;
        psum += p;
        P[qq][pp * 16 + i] = __float2bfloat16(p);
      }
      red[pp][qq] = psum;
    }
    __syncthreads();
    if (pp == 0) {
      s_run[qq] = s_run[qq] * alpha_l[qq] +
                  ((red[0][qq] + red[1][qq]) + (red[2][qq] + red[3][qq]));
    }
    {
      const bf16* Vp = Vt + (size_t)(wave * 16 + l15) * N_N + kb;
      bf16x8 vf0 = *(const bf16x8*)(Vp + g8);
      bf16x8 vf1 = *(const bf16x8*)(Vp + 32 + g8);
#pragma unroll
      for (int qsub = 0; qsub < 4; ++qsub) {
        float al = alpha_l[qsub * 16 + l15];
        acc[qsub][0] *= al; acc[qsub][1] *= al;
        acc[qsub][2] *= al; acc[qsub][3] *= al;
        bf16x8 pf0 = *(const bf16x8*)(&P[qsub * 16 + l15][g8]);
        bf16x8 pf1 = *(const bf16x8*)(&P[qsub * 16 + l15][32 + g8]);
        acc[qsub] = mfma32(vf0, pf0, acc[qsub]);
        acc[qsub] = mfma32(vf1, pf1, acc[qsub]);
      }
    }
    __syncthreads();
  }
#pragma unroll
  for (int qsub = 0; qsub < 4; ++qsub) {
    float sr = s_run[qsub * 16 + l15];
    float inv = (sr > 0.f) ? (1.f / sr) : 0.f;
    bf16x4 pk = {bfs(acc[qsub][0] * inv), bfs(acc[qsub][1] * inv),
                 bfs(acc[qsub][2] * inv), bfs(acc[qsub][3] * inv)};
    bf16* Op = ao + ((size_t)b * N_N + q0 + qsub * 16 + l15) * 256 +
               h * 64 + wave * 16 + g * 4;
    *reinterpret_cast<bf16x4*>(Op) = pk;
  }
}

// ---------------- proj GEMM (MFMA) + bias + residual, fp32 out --------------
__global__ __launch_bounds__(256) void proj_gemm(const bf16* __restrict__ wpb,
                                                 const bf16* __restrict__ ao,
                                                 const float* __restrict__ bproj,
                                                 const float* __restrict__ x,
                                                 float* __restrict__ out) {
  int id = blockIdx.x;               // 576 = 18nt * 4ot * 8b
  int nt = id % 18, ot = (id / 18) & 3, b = id / 72;
  int o0 = ot * 64, n0 = nt * 128;
  int lane = threadIdx.x & 63, wave = threadIdx.x >> 6;
  int l15 = lane & 15, g = lane >> 4, g8 = g * 8;
  const bf16* Ab = wpb + (size_t)(o0 + l15) * 256 + g8;
  const bf16* Bb = ao + ((size_t)b * N_N + n0 + wave * 32 + l15) * 256 + g8;
  f32x4 z = {0.f, 0.f, 0.f, 0.f};
  f32x4 acc[4][2];
#pragma unroll
  for (int i = 0; i < 4; ++i) { acc[i][0] = z; acc[i][1] = z; }
#pragma unroll
  for (int kk = 0; kk < 8; ++kk) {
    int co = kk * 32;
    bf16x8 b0 = *(const bf16x8*)(Bb + co);
    bf16x8 b1 = *(const bf16x8*)(Bb + 16 * 256 + co);
#pragma unroll
    for (int mb = 0; mb < 4; ++mb) {
      bf16x8 aa = *(const bf16x8*)(Ab + mb * 4096 + co);
      acc[mb][0] = mfma32(aa, b0, acc[mb][0]);
      acc[mb][1] = mfma32(aa, b1, acc[mb][1]);
    }
  }
  int jb = n0 + wave * 32;
#pragma unroll
  for (int mb = 0; mb < 4; ++mb) {
    int ob = o0 + mb * 16 + g * 4;
    f32x4 bp = *(const f32x4*)(bproj + ob);
#pragma unroll
    for (int nb = 0; nb < 2; ++nb) {
      int n = jb + nb * 16 + l15;
#pragma unroll
      for (int r = 0; r < 4; ++r) {
        size_t idx = ((size_t)b * 256 + ob + r) * N_N + n;
        out[idx] = acc[mb][nb][r] + bp[r] + x[idx];
      }
    }
  }
}

// ---------------- host launch ------------------------------------------------
extern "C" void kernel_launch(void* const* d_in, const int* in_sizes, int n_in,
                              void* d_out, int out_size, void* d_ws, size_t ws_size,
                              hipStream_t stream) {
  (void)in_sizes; (void)n_in; (void)out_size; (void)ws_size;
  const float* x     = (const float*)d_in[0];
  const int*   mask  = (const int*)d_in[1];
  const float* gnw   = (const float*)d_in[2];
  const float* gnb   = (const float*)d_in[3];
  const float* wqkv  = (const float*)d_in[4];
  const float* wproj = (const float*)d_in[5];
  const float* bproj = (const float*)d_in[6];
  float* out = (float*)d_out;
  char* ws = (char*)d_ws;

  float* part = (float*)(ws + 0);                  // 2048 B
  float* mr   = (float*)(ws + 2048);               // 64 B
  bf16*  wqb  = (bf16*)(ws + 4096);                // 393216 B
  bf16*  wpb  = (bf16*)(ws + 397312);              // 131072 B
  bf16*  xt   = (bf16*)(ws + 528384);              // 9437184 B (reused as ao)
  bf16*  qkv  = (bf16*)(ws + 9965568);             // 28311552 B -> end ~36.5 MB
  bf16*  ao   = xt;  // xt dead after qkv_mfma

  gn_stats<<<256, 256, 0, stream>>>(x, part);
  stats_final<<<1, 64, 0, stream>>>(part, mr);
  wq_conv<<<768, 256, 0, stream>>>(wqkv, wqb);
  wp_conv<<<256, 256, 0, stream>>>(wproj, wpb);
  xt_gn<<<1152, 256, 0, stream>>>(x, mr, gnw, gnb, xt);
  qkv_mfma<<<1728, 256, 0, stream>>>(wqb, xt, qkv);
  attn_mfma<<<1152, 256, 0, stream>>>(qkv, mask, ao);
  proj_gemm<<<576, 256, 0, stream>>>(wpb, ao, bproj, x, out);
}

// Round 9
// 278.112 us; speedup vs baseline: 15.8990x; 1.1219x over previous
//
#include <hip/hip_runtime.h>
#include <hip/hip_bf16.h>

typedef __hip_bfloat16 bf16;
typedef short bf16x4 __attribute__((ext_vector_type(4)));
typedef short bf16x8 __attribute__((ext_vector_type(8)));
typedef float f32x4 __attribute__((ext_vector_type(4)));

#define N_B 8
#define N_C 256
#define N_H 4
#define N_N 2304
#define N_ELEM 589824   // N_C * N_N

static __device__ __forceinline__ f32x4 mfma32(bf16x8 a, bf16x8 b, f32x4 c) {
  return __builtin_amdgcn_mfma_f32_16x16x32_bf16(a, b, c, 0, 0, 0);
}
static __device__ __forceinline__ short bfs(float f) {
  union { __hip_bfloat16 h; short s; } u;
  u.h = __float2bfloat16(f);
  return u.s;
}

// ---------------- GN stats: partial sums per (batch, chunk) -----------------
__global__ __launch_bounds__(256) void gn_stats(const float* __restrict__ x,
                                                float* __restrict__ part) {
  int b = blockIdx.x >> 5, chunk = blockIdx.x & 31;
  const f32x4* p = (const f32x4*)(x + (size_t)b * N_ELEM + (size_t)chunk * 18432);
  float s = 0.f, ss = 0.f;
  for (int i = threadIdx.x; i < 4608; i += 256) {
    f32x4 v = p[i];
    s  += (v[0] + v[1]) + (v[2] + v[3]);
    ss += (v[0] * v[0] + v[1] * v[1]) + (v[2] * v[2] + v[3] * v[3]);
  }
  for (int off = 32; off; off >>= 1) {
    s  += __shfl_xor(s, off);
    ss += __shfl_xor(ss, off);
  }
  __shared__ float ls[8];
  int wv = threadIdx.x >> 6;
  if ((threadIdx.x & 63) == 0) { ls[wv] = s; ls[4 + wv] = ss; }
  __syncthreads();
  if (threadIdx.x == 0) {
    part[blockIdx.x * 2]     = ls[0] + ls[1] + ls[2] + ls[3];
    part[blockIdx.x * 2 + 1] = ls[4] + ls[5] + ls[6] + ls[7];
  }
}

__global__ void stats_final(const float* __restrict__ part, float* __restrict__ mr) {
  int b = threadIdx.x;
  if (b < N_B) {
    float s = 0.f, ss = 0.f;
    for (int i = 0; i < 32; ++i) {
      s  += part[b * 64 + i * 2];
      ss += part[b * 64 + i * 2 + 1];
    }
    float mean = s * (1.f / (float)N_ELEM);
    float var  = ss * (1.f / (float)N_ELEM) - mean * mean;
    mr[b * 2]     = mean;
    mr[b * 2 + 1] = rsqrtf(var + 1e-5f);
  }
}

// ---------------- weight converts -------------------------------------------
__global__ __launch_bounds__(256) void wq_conv(const float* __restrict__ wq,
                                               bf16* __restrict__ wqb) {
  int i = blockIdx.x * 256 + threadIdx.x;
  int row = i >> 8;
  float sc = (row < 256) ? 0.125f : 1.0f;   // exact 2^-3 into Q rows
  wqb[i] = __float2bfloat16(wq[i] * sc);
}

__global__ __launch_bounds__(256) void wp_conv(const float* __restrict__ wp,
                                               bf16* __restrict__ wpb) {
  int i = blockIdx.x * 256 + threadIdx.x;
  wpb[i] = __float2bfloat16(wp[i]);
}

// ---------------- fused GN + transpose: x[b][c][n] f32 -> xt[b][n][c] bf16 --
__global__ __launch_bounds__(256) void xt_gn(const float* __restrict__ x,
                                             const float* __restrict__ mr,
                                             const float* __restrict__ gnw,
                                             const float* __restrict__ gnb,
                                             bf16* __restrict__ xt) {
  int id = blockIdx.x;               // 1152 = 36nt * 4ct * 8b
  int nt = id % 36, ct = (id / 36) & 3, b = id / 144;
  float mean = mr[b * 2], rstd = mr[b * 2 + 1];
  __shared__ bf16 tile[64][65];
  int tn = threadIdx.x & 63, tq = threadIdx.x >> 6;
  const float* xp = x + (size_t)b * N_ELEM + (size_t)(ct * 64) * N_N + nt * 64;
  for (int it = 0; it < 16; ++it) {
    int c = tq * 16 + it;
    int cg = ct * 64 + c;
    float a  = rstd * gnw[cg];
    float dd = gnb[cg] - mean * a;
    tile[c][tn] = __float2bfloat16(xp[(size_t)c * N_N + tn] * a + dd);
  }
  __syncthreads();
  bf16* xo = xt + ((size_t)b * N_N + nt * 64) * 256 + ct * 64;
  for (int it = 0; it < 16; ++it) {
    int nl = tq * 16 + it;
    xo[(size_t)nl * 256 + tn] = tile[tn][nl];
  }
}

// ---------------- QKV GEMM (MFMA, verified pattern; XCD-swizzled grid) ------
__global__ __launch_bounds__(256) void qkv_mfma(const bf16* __restrict__ wqb,
                                                const bf16* __restrict__ xt,
                                                bf16* __restrict__ qkv) {
  // bijective XCD swizzle: 1728 % 8 == 0; each XCD gets one batch's panel
  int id = (blockIdx.x & 7) * 216 + (blockIdx.x >> 3);
  int nt = id % 18, ot = (id / 18) % 12, b = id / 216;
  int o0 = ot * 64, n0 = nt * 128;
  int lane = threadIdx.x & 63, wave = threadIdx.x >> 6;
  int l15 = lane & 15, g = lane >> 4, g8 = g * 8;
  const bf16* Ab = wqb + (size_t)(o0 + l15) * 256 + g8;
  const bf16* Bb = xt + ((size_t)b * N_N + n0 + wave * 32 + l15) * 256 + g8;
  f32x4 z = {0.f, 0.f, 0.f, 0.f};
  f32x4 acc[4][2];
#pragma unroll
  for (int i = 0; i < 4; ++i) { acc[i][0] = z; acc[i][1] = z; }
#pragma unroll
  for (int kk = 0; kk < 8; ++kk) {
    int co = kk * 32;
    bf16x8 b0 = *(const bf16x8*)(Bb + co);
    bf16x8 b1 = *(const bf16x8*)(Bb + 16 * 256 + co);
#pragma unroll
    for (int mb = 0; mb < 4; ++mb) {
      bf16x8 aa = *(const bf16x8*)(Ab + mb * 4096 + co);
      acc[mb][0] = mfma32(aa, b0, acc[mb][0]);
      acc[mb][1] = mfma32(aa, b1, acc[mb][1]);
    }
  }
  int seg = o0 >> 8, h = (o0 >> 6) & 3;
  int jb = n0 + wave * 32;
  bf16* Base = qkv + ((size_t)seg * (N_B * N_H) + (size_t)b * N_H + h) *
               ((size_t)N_N * 64);
  if (seg < 2) {
#pragma unroll
    for (int mb = 0; mb < 4; ++mb) {
#pragma unroll
      for (int nb = 0; nb < 2; ++nb) {
        int row = jb + nb * 16 + l15;
        int d0 = mb * 16 + g * 4;
        bf16x4 pk = {bfs(acc[mb][nb][0]), bfs(acc[mb][nb][1]),
                     bfs(acc[mb][nb][2]), bfs(acc[mb][nb][3])};
        *reinterpret_cast<bf16x4*>(Base + (size_t)row * 64 + d0) = pk;
      }
    }
  } else {
#pragma unroll
    for (int mb = 0; mb < 4; ++mb) {
#pragma unroll
      for (int nb = 0; nb < 2; ++nb) {
        int n = jb + nb * 16 + l15;
#pragma unroll
        for (int r = 0; r < 4; ++r) {
          int d = mb * 16 + g * 4 + r;
          Base[(size_t)d * N_N + n] = __float2bfloat16(acc[mb][nb][r]);
        }
      }
    }
  }
}

// ---------------- MFMA flash attention (P XOR-swizzled, XCD-swizzled) -------
__global__ __launch_bounds__(256) void attn_mfma(const bf16* __restrict__ qkv,
                                                 const int* __restrict__ mask,
                                                 bf16* __restrict__ ao) {
  // bijective XCD swizzle: 1152 % 8 == 0; each XCD gets 4 contiguous (b,h)
  int id = (blockIdx.x & 7) * 144 + (blockIdx.x >> 3);
  int qt = id % 36, h = (id / 36) & 3, b = id / 144;
  int tid = threadIdx.x;
  int lane = tid & 63, wave = tid >> 6;
  int l15 = lane & 15, g = lane >> 4, g8 = g * 8;
  int q0 = qt * 64;
  const size_t HSZ = (size_t)N_N * 64;
  const bf16* Qb = qkv + ((size_t)b * N_H + h) * HSZ;
  const bf16* Kb = qkv + ((size_t)(N_B * N_H) + (size_t)b * N_H + h) * HSZ;
  const bf16* Vt = qkv + ((size_t)(2 * N_B * N_H) + (size_t)b * N_H + h) * HSZ;
  const int* mb = mask + b * N_N;

  __shared__ float S[64][68];
  __shared__ bf16 P[64 * 64];          // row-major 64x64, 16B-chunk XOR swizzle
  __shared__ float m_run[64], s_run[64], alpha_l[64], red[4][64];
  bf16x8* Pv = (bf16x8*)P;             // 8 chunks of 16B per row
  if (tid < 64) { m_run[tid] = -3.0e38f; s_run[tid] = 0.f; }
  __syncthreads();

  bf16x8 qf[4][2];
#pragma unroll
  for (int qsub = 0; qsub < 4; ++qsub) {
    const bf16* Qp = Qb + (size_t)(q0 + qsub * 16 + l15) * 64;
    qf[qsub][0] = *(const bf16x8*)(Qp + g8);
    qf[qsub][1] = *(const bf16x8*)(Qp + 32 + g8);
  }
  f32x4 z = {0.f, 0.f, 0.f, 0.f};
  f32x4 acc[4];
#pragma unroll
  for (int i = 0; i < 4; ++i) acc[i] = z;
  int qq = tid & 63, pp = tid >> 6;

  for (int kb = 0; kb < N_N; kb += 64) {
    {
      const bf16* Kp = Kb + (size_t)(kb + wave * 16 + l15) * 64;
      bf16x8 kf0 = *(const bf16x8*)(Kp + g8);
      bf16x8 kf1 = *(const bf16x8*)(Kp + 32 + g8);
#pragma unroll
      for (int qsub = 0; qsub < 4; ++qsub) {
        f32x4 s = z;
        s = mfma32(kf0, qf[qsub][0], s);
        s = mfma32(kf1, qf[qsub][1], s);
#pragma unroll
        for (int r = 0; r < 4; ++r)
          S[wave * 16 + g * 4 + r][qsub * 16 + l15] = s[r];
      }
    }
    __syncthreads();
    float sv[16];
    int valid[16];
    float lmax = -3.0e38f;
#pragma unroll
    for (int i = 0; i < 16; ++i) {
      int k = pp * 16 + i;
      valid[i] = mb[kb + k];
      sv[i] = S[k][qq];
      if (valid[i]) lmax = fmaxf(lmax, sv[i]);
    }
    red[pp][qq] = lmax;
    __syncthreads();
    if (pp == 0) {
      float mnew = fmaxf(fmaxf(m_run[qq], red[0][qq]),
                         fmaxf(red[1][qq], fmaxf(red[2][qq], red[3][qq])));
      alpha_l[qq] = expf(m_run[qq] - mnew);
      m_run[qq] = mnew;
    }
    __syncthreads();
    {
      float mnew = m_run[qq];
      float psum = 0.f;
      float pv[16];
#pragma unroll
      for (int i = 0; i < 16; ++i) {
        pv[i] = valid[i] ? expf(sv[i] - mnew) : 0.f;
        psum += pv[i];
      }
      // vectorized swizzled P write: thread owns row qq, chunks pp*2, pp*2+1
      bf16x8 w0 = {bfs(pv[0]), bfs(pv[1]), bfs(pv[2]), bfs(pv[3]),
                   bfs(pv[4]), bfs(pv[5]), bfs(pv[6]), bfs(pv[7])};
      bf16x8 w1 = {bfs(pv[8]),  bfs(pv[9]),  bfs(pv[10]), bfs(pv[11]),
                   bfs(pv[12]), bfs(pv[13]), bfs(pv[14]), bfs(pv[15])};
      int r7 = qq & 7;
      Pv[qq * 8 + ((pp * 2)     ^ r7)] = w0;
      Pv[qq * 8 + ((pp * 2 + 1) ^ r7)] = w1;
      red[pp][qq] = psum;
    }
    __syncthreads();
    if (pp == 0) {
      s_run[qq] = s_run[qq] * alpha_l[qq] +
                  ((red[0][qq] + red[1][qq]) + (red[2][qq] + red[3][qq]));
    }
    {
      const bf16* Vp = Vt + (size_t)(wave * 16 + l15) * N_N + kb;
      bf16x8 vf0 = *(const bf16x8*)(Vp + g8);
      bf16x8 vf1 = *(const bf16x8*)(Vp + 32 + g8);
#pragma unroll
      for (int qsub = 0; qsub < 4; ++qsub) {
        float al = alpha_l[qsub * 16 + l15];
        acc[qsub][0] *= al; acc[qsub][1] *= al;
        acc[qsub][2] *= al; acc[qsub][3] *= al;
        int rq = qsub * 16 + l15, rr7 = rq & 7;
        bf16x8 pf0 = Pv[rq * 8 + (g ^ rr7)];
        bf16x8 pf1 = Pv[rq * 8 + ((4 + g) ^ rr7)];
        acc[qsub] = mfma32(vf0, pf0, acc[qsub]);
        acc[qsub] = mfma32(vf1, pf1, acc[qsub]);
      }
    }
    __syncthreads();
  }
#pragma unroll
  for (int qsub = 0; qsub < 4; ++qsub) {
    float sr = s_run[qsub * 16 + l15];
    float inv = (sr > 0.f) ? (1.f / sr) : 0.f;
    bf16x4 pk = {bfs(acc[qsub][0] * inv), bfs(acc[qsub][1] * inv),
                 bfs(acc[qsub][2] * inv), bfs(acc[qsub][3] * inv)};
    bf16* Op = ao + ((size_t)b * N_N + q0 + qsub * 16 + l15) * 256 +
               h * 64 + wave * 16 + g * 4;
    *reinterpret_cast<bf16x4*>(Op) = pk;
  }
}

// ---------------- proj GEMM (MFMA) + bias + residual, fp32 out --------------
__global__ __launch_bounds__(256) void proj_gemm(const bf16* __restrict__ wpb,
                                                 const bf16* __restrict__ ao,
                                                 const float* __restrict__ bproj,
                                                 const float* __restrict__ x,
                                                 float* __restrict__ out) {
  // bijective XCD swizzle: 576 % 8 == 0; one batch per XCD
  int id = (blockIdx.x & 7) * 72 + (blockIdx.x >> 3);
  int nt = id % 18, ot = (id / 18) & 3, b = id / 72;
  int o0 = ot * 64, n0 = nt * 128;
  int lane = threadIdx.x & 63, wave = threadIdx.x >> 6;
  int l15 = lane & 15, g = lane >> 4, g8 = g * 8;
  const bf16* Ab = wpb + (size_t)(o0 + l15) * 256 + g8;
  const bf16* Bb = ao + ((size_t)b * N_N + n0 + wave * 32 + l15) * 256 + g8;
  f32x4 z = {0.f, 0.f, 0.f, 0.f};
  f32x4 acc[4][2];
#pragma unroll
  for (int i = 0; i < 4; ++i) { acc[i][0] = z; acc[i][1] = z; }
#pragma unroll
  for (int kk = 0; kk < 8; ++kk) {
    int co = kk * 32;
    bf16x8 b0 = *(const bf16x8*)(Bb + co);
    bf16x8 b1 = *(const bf16x8*)(Bb + 16 * 256 + co);
#pragma unroll
    for (int mb = 0; mb < 4; ++mb) {
      bf16x8 aa = *(const bf16x8*)(Ab + mb * 4096 + co);
      acc[mb][0] = mfma32(aa, b0, acc[mb][0]);
      acc[mb][1] = mfma32(aa, b1, acc[mb][1]);
    }
  }
  int jb = n0 + wave * 32;
#pragma unroll
  for (int mb = 0; mb < 4; ++mb) {
    int ob = o0 + mb * 16 + g * 4;
    f32x4 bp = *(const f32x4*)(bproj + ob);
#pragma unroll
    for (int nb = 0; nb < 2; ++nb) {
      int n = jb + nb * 16 + l15;
#pragma unroll
      for (int r = 0; r < 4; ++r) {
        size_t idx = ((size_t)b * 256 + ob + r) * N_N + n;
        out[idx] = acc[mb][nb][r] + bp[r] + x[idx];
      }
    }
  }
}

// ---------------- host launch ------------------------------------------------
extern "C" void kernel_launch(void* const* d_in, const int* in_sizes, int n_in,
                              void* d_out, int out_size, void* d_ws, size_t ws_size,
                              hipStream_t stream) {
  (void)in_sizes; (void)n_in; (void)out_size; (void)ws_size;
  const float* x     = (const float*)d_in[0];
  const int*   mask  = (const int*)d_in[1];
  const float* gnw   = (const float*)d_in[2];
  const float* gnb   = (const float*)d_in[3];
  const float* wqkv  = (const float*)d_in[4];
  const float* wproj = (const float*)d_in[5];
  const float* bproj = (const float*)d_in[6];
  float* out = (float*)d_out;
  char* ws = (char*)d_ws;

  float* part = (float*)(ws + 0);                  // 2048 B
  float* mr   = (float*)(ws + 2048);               // 64 B
  bf16*  wqb  = (bf16*)(ws + 4096);                // 393216 B
  bf16*  wpb  = (bf16*)(ws + 397312);              // 131072 B
  bf16*  xt   = (bf16*)(ws + 528384);              // 9437184 B (reused as ao)
  bf16*  qkv  = (bf16*)(ws + 9965568);             // 28311552 B -> end ~36.5 MB
  bf16*  ao   = xt;  // xt dead after qkv_mfma

  gn_stats<<<256, 256, 0, stream>>>(x, part);
  stats_final<<<1, 64, 0, stream>>>(part, mr);
  wq_conv<<<768, 256, 0, stream>>>(wqkv, wqb);
  wp_conv<<<256, 256, 0, stream>>>(wproj, wpb);
  xt_gn<<<1152, 256, 0, stream>>>(x, mr, gnw, gnb, xt);
  qkv_mfma<<<1728, 256, 0, stream>>>(wqb, xt, qkv);
  attn_mfma<<<1152, 256, 0, stream>>>(qkv, mask, ao);
  proj_gemm<<<576, 256, 0, stream>>>(wpb, ao, bproj, x, out);
}

// Round 10
// 228.597 us; speedup vs baseline: 19.3428x; 1.2166x over previous
//
#include <hip/hip_runtime.h>
#include <hip/hip_bf16.h>

typedef __hip_bfloat16 bf16;
typedef short bf16x4 __attribute__((ext_vector_type(4)));
typedef short bf16x8 __attribute__((ext_vector_type(8)));
typedef float f32x4 __attribute__((ext_vector_type(4)));

#define N_B 8
#define N_C 256
#define N_H 4
#define N_N 2304
#define N_ELEM 589824   // N_C * N_N

static __device__ __forceinline__ f32x4 mfma32(bf16x8 a, bf16x8 b, f32x4 c) {
  return __builtin_amdgcn_mfma_f32_16x16x32_bf16(a, b, c, 0, 0, 0);
}
static __device__ __forceinline__ short bfs(float f) {
  union { __hip_bfloat16 h; short s; } u;
  u.h = __float2bfloat16(f);
  return u.s;
}

// ---------------- GN stats: partial sums per (batch, chunk) -----------------
__global__ __launch_bounds__(256) void gn_stats(const float* __restrict__ x,
                                                float* __restrict__ part) {
  int b = blockIdx.x >> 5, chunk = blockIdx.x & 31;
  const f32x4* p = (const f32x4*)(x + (size_t)b * N_ELEM + (size_t)chunk * 18432);
  float s = 0.f, ss = 0.f;
  for (int i = threadIdx.x; i < 4608; i += 256) {
    f32x4 v = p[i];
    s  += (v[0] + v[1]) + (v[2] + v[3]);
    ss += (v[0] * v[0] + v[1] * v[1]) + (v[2] * v[2] + v[3] * v[3]);
  }
  for (int off = 32; off; off >>= 1) {
    s  += __shfl_xor(s, off);
    ss += __shfl_xor(ss, off);
  }
  __shared__ float ls[8];
  int wv = threadIdx.x >> 6;
  if ((threadIdx.x & 63) == 0) { ls[wv] = s; ls[4 + wv] = ss; }
  __syncthreads();
  if (threadIdx.x == 0) {
    part[blockIdx.x * 2]     = ls[0] + ls[1] + ls[2] + ls[3];
    part[blockIdx.x * 2 + 1] = ls[4] + ls[5] + ls[6] + ls[7];
  }
}

__global__ void stats_final(const float* __restrict__ part, float* __restrict__ mr) {
  int b = threadIdx.x;
  if (b < N_B) {
    float s = 0.f, ss = 0.f;
    for (int i = 0; i < 32; ++i) {
      s  += part[b * 64 + i * 2];
      ss += part[b * 64 + i * 2 + 1];
    }
    float mean = s * (1.f / (float)N_ELEM);
    float var  = ss * (1.f / (float)N_ELEM) - mean * mean;
    mr[b * 2]     = mean;
    mr[b * 2 + 1] = rsqrtf(var + 1e-5f);
  }
}

// ---------------- weight converts -------------------------------------------
__global__ __launch_bounds__(256) void wq_conv(const float* __restrict__ wq,
                                               bf16* __restrict__ wqb) {
  int i = blockIdx.x * 256 + threadIdx.x;
  int row = i >> 8;
  // Q rows: fold head_dim^-0.5 * log2(e) so softmax uses exp2
  float sc = (row < 256) ? 0.18033688011112042f : 1.0f;
  wqb[i] = __float2bfloat16(wq[i] * sc);
}

__global__ __launch_bounds__(256) void wp_conv(const float* __restrict__ wp,
                                               bf16* __restrict__ wpb) {
  int i = blockIdx.x * 256 + threadIdx.x;
  wpb[i] = __float2bfloat16(wp[i]);
}

// ---------------- fused GN + transpose: x[b][c][n] f32 -> xt[b][n][c] bf16 --
__global__ __launch_bounds__(256) void xt_gn(const float* __restrict__ x,
                                             const float* __restrict__ mr,
                                             const float* __restrict__ gnw,
                                             const float* __restrict__ gnb,
                                             bf16* __restrict__ xt) {
  int id = blockIdx.x;               // 1152 = 36nt * 4ct * 8b
  int nt = id % 36, ct = (id / 36) & 3, b = id / 144;
  float mean = mr[b * 2], rstd = mr[b * 2 + 1];
  __shared__ bf16 tile[64][65];
  int tn = threadIdx.x & 63, tq = threadIdx.x >> 6;
  const float* xp = x + (size_t)b * N_ELEM + (size_t)(ct * 64) * N_N + nt * 64;
  for (int it = 0; it < 16; ++it) {
    int c = tq * 16 + it;
    int cg = ct * 64 + c;
    float a  = rstd * gnw[cg];
    float dd = gnb[cg] - mean * a;
    tile[c][tn] = __float2bfloat16(xp[(size_t)c * N_N + tn] * a + dd);
  }
  __syncthreads();
  bf16* xo = xt + ((size_t)b * N_N + nt * 64) * 256 + ct * 64;
  for (int it = 0; it < 16; ++it) {
    int nl = tq * 16 + it;
    xo[(size_t)nl * 256 + tn] = tile[tn][nl];
  }
}

// ---------------- QKV GEMM (MFMA, verified pattern; XCD-swizzled grid) ------
__global__ __launch_bounds__(256) void qkv_mfma(const bf16* __restrict__ wqb,
                                                const bf16* __restrict__ xt,
                                                bf16* __restrict__ qkv) {
  int id = (blockIdx.x & 7) * 216 + (blockIdx.x >> 3);
  int nt = id % 18, ot = (id / 18) % 12, b = id / 216;
  int o0 = ot * 64, n0 = nt * 128;
  int lane = threadIdx.x & 63, wave = threadIdx.x >> 6;
  int l15 = lane & 15, g = lane >> 4, g8 = g * 8;
  const bf16* Ab = wqb + (size_t)(o0 + l15) * 256 + g8;
  const bf16* Bb = xt + ((size_t)b * N_N + n0 + wave * 32 + l15) * 256 + g8;
  f32x4 z = {0.f, 0.f, 0.f, 0.f};
  f32x4 acc[4][2];
#pragma unroll
  for (int i = 0; i < 4; ++i) { acc[i][0] = z; acc[i][1] = z; }
#pragma unroll
  for (int kk = 0; kk < 8; ++kk) {
    int co = kk * 32;
    bf16x8 b0 = *(const bf16x8*)(Bb + co);
    bf16x8 b1 = *(const bf16x8*)(Bb + 16 * 256 + co);
#pragma unroll
    for (int mb = 0; mb < 4; ++mb) {
      bf16x8 aa = *(const bf16x8*)(Ab + mb * 4096 + co);
      acc[mb][0] = mfma32(aa, b0, acc[mb][0]);
      acc[mb][1] = mfma32(aa, b1, acc[mb][1]);
    }
  }
  int seg = o0 >> 8, h = (o0 >> 6) & 3;
  int jb = n0 + wave * 32;
  bf16* Base = qkv + ((size_t)seg * (N_B * N_H) + (size_t)b * N_H + h) *
               ((size_t)N_N * 64);
  if (seg < 2) {
#pragma unroll
    for (int mb = 0; mb < 4; ++mb) {
#pragma unroll
      for (int nb = 0; nb < 2; ++nb) {
        int row = jb + nb * 16 + l15;
        int d0 = mb * 16 + g * 4;
        bf16x4 pk = {bfs(acc[mb][nb][0]), bfs(acc[mb][nb][1]),
                     bfs(acc[mb][nb][2]), bfs(acc[mb][nb][3])};
        *reinterpret_cast<bf16x4*>(Base + (size_t)row * 64 + d0) = pk;
      }
    }
  } else {
#pragma unroll
    for (int mb = 0; mb < 4; ++mb) {
#pragma unroll
      for (int nb = 0; nb < 2; ++nb) {
        int n = jb + nb * 16 + l15;
#pragma unroll
        for (int r = 0; r < 4; ++r) {
          int d = mb * 16 + g * 4 + r;
          Base[(size_t)d * N_N + n] = __float2bfloat16(acc[mb][nb][r]);
        }
      }
    }
  }
}

// ---------------- register-softmax flash attention --------------------------
// Wave w owns keys {n : n%64 in [16w,16w+16)}. Main loop: NO barriers, NO LDS.
// S-mfma (A=K rows, B=Q rows) leaves lane (g,l15) with P[key=base+g*4+r][q=
// qsub*16+l15]; PV uses the SAME key->slot bijection on V (A) and P (B):
// slot(g,i) = key base + 64*(i>>2) + g*4 + (i&3). One LDS merge at the end.
__global__ __launch_bounds__(256, 2) void attn_reg(const bf16* __restrict__ qkv,
                                                   const int* __restrict__ mask,
                                                   bf16* __restrict__ ao) {
  int id = (blockIdx.x & 7) * 144 + (blockIdx.x >> 3);
  int qt = id % 36, h = (id / 36) & 3, b = id / 144;
  int tid = threadIdx.x;
  int lane = tid & 63, wave = tid >> 6;
  int l15 = lane & 15, g = lane >> 4, g8 = g * 8;
  int q0 = qt * 64;
  const size_t HSZ = (size_t)N_N * 64;
  const bf16* Qb = qkv + ((size_t)b * N_H + h) * HSZ;
  const bf16* Kb = qkv + ((size_t)(N_B * N_H) + (size_t)b * N_H + h) * HSZ;
  const bf16* Vt = qkv + ((size_t)(2 * N_B * N_H) + (size_t)b * N_H + h) * HSZ;
  const int* mb = mask + b * N_N;

  __shared__ float msh[4][64], ssh[4][64];
  __shared__ float obuf[64][65];

  // loop-invariant Q fragments (B-operand rows q0+qsub*16+l15)
  bf16x8 qf[4][2];
#pragma unroll
  for (int qsub = 0; qsub < 4; ++qsub) {
    const bf16* Qp = Qb + (size_t)(q0 + qsub * 16 + l15) * 64;
    qf[qsub][0] = *(const bf16x8*)(Qp + g8);
    qf[qsub][1] = *(const bf16x8*)(Qp + 32 + g8);
  }
  f32x4 z = {0.f, 0.f, 0.f, 0.f};
  f32x4 acc[4][4];   // [dblock][qsub]: O[d=dblock*16+g*4+r][q=qsub*16+l15]
#pragma unroll
  for (int i = 0; i < 4; ++i)
#pragma unroll
    for (int j = 0; j < 4; ++j) acc[i][j] = z;
  float m_r[4] = {-3.0e38f, -3.0e38f, -3.0e38f, -3.0e38f};
  float s_r[4] = {0.f, 0.f, 0.f, 0.f};

  int kw = wave * 16;                // wave's key offset within each 64-tile
  for (int kb = 0; kb < N_N; kb += 128) {
    const bf16* Kp0 = Kb + (size_t)(kb + kw + l15) * 64;
    const bf16* Kp1 = Kb + (size_t)(kb + 64 + kw + l15) * 64;
    bf16x8 k0lo = *(const bf16x8*)(Kp0 + g8);
    bf16x8 k0hi = *(const bf16x8*)(Kp0 + 32 + g8);
    bf16x8 k1lo = *(const bf16x8*)(Kp1 + g8);
    bf16x8 k1hi = *(const bf16x8*)(Kp1 + 32 + g8);
    int4 mv0 = *(const int4*)(mb + kb + kw + g * 4);
    int4 mv1 = *(const int4*)(mb + kb + 64 + kw + g * 4);

    bf16x8 pb[4];
    float alpha_r[4];
#pragma unroll
    for (int qsub = 0; qsub < 4; ++qsub) {
      f32x4 s0 = z, s1 = z;
      s0 = mfma32(k0lo, qf[qsub][0], s0);
      s0 = mfma32(k0hi, qf[qsub][1], s0);
      s1 = mfma32(k1lo, qf[qsub][0], s1);
      s1 = mfma32(k1hi, qf[qsub][1], s1);
      const float NEG = -3.0e38f;
      float a0 = mv0.x ? s0[0] : NEG, a1 = mv0.y ? s0[1] : NEG;
      float a2 = mv0.z ? s0[2] : NEG, a3 = mv0.w ? s0[3] : NEG;
      float a4 = mv1.x ? s1[0] : NEG, a5 = mv1.y ? s1[1] : NEG;
      float a6 = mv1.z ? s1[2] : NEG, a7 = mv1.w ? s1[3] : NEG;
      float pmax = fmaxf(fmaxf(fmaxf(a0, a1), fmaxf(a2, a3)),
                         fmaxf(fmaxf(a4, a5), fmaxf(a6, a7)));
      pmax = fmaxf(pmax, __shfl_xor(pmax, 16));
      pmax = fmaxf(pmax, __shfl_xor(pmax, 32));
      float mnew = fmaxf(m_r[qsub], pmax);
      float alpha = exp2f(m_r[qsub] - mnew);
      float p0 = mv0.x ? exp2f(s0[0] - mnew) : 0.f;
      float p1 = mv0.y ? exp2f(s0[1] - mnew) : 0.f;
      float p2 = mv0.z ? exp2f(s0[2] - mnew) : 0.f;
      float p3 = mv0.w ? exp2f(s0[3] - mnew) : 0.f;
      float p4 = mv1.x ? exp2f(s1[0] - mnew) : 0.f;
      float p5 = mv1.y ? exp2f(s1[1] - mnew) : 0.f;
      float p6 = mv1.z ? exp2f(s1[2] - mnew) : 0.f;
      float p7 = mv1.w ? exp2f(s1[3] - mnew) : 0.f;
      float psum = ((p0 + p1) + (p2 + p3)) + ((p4 + p5) + (p6 + p7));
      psum += __shfl_xor(psum, 16);
      psum += __shfl_xor(psum, 32);
      s_r[qsub] = s_r[qsub] * alpha + psum;
      m_r[qsub] = mnew;
      alpha_r[qsub] = alpha;
      pb[qsub] = bf16x8{bfs(p0), bfs(p1), bfs(p2), bfs(p3),
                        bfs(p4), bfs(p5), bfs(p6), bfs(p7)};
    }
    // PV: A = V^T, same slot bijection; D rows = d-block rows
#pragma unroll
    for (int dblock = 0; dblock < 4; ++dblock) {
      const bf16* Vp = Vt + (size_t)(dblock * 16 + l15) * N_N;
      bf16x4 v0 = *(const bf16x4*)(Vp + kb + kw + g * 4);
      bf16x4 v1 = *(const bf16x4*)(Vp + kb + 64 + kw + g * 4);
      bf16x8 vf = {v0[0], v0[1], v0[2], v0[3], v1[0], v1[1], v1[2], v1[3]};
#pragma unroll
      for (int qsub = 0; qsub < 4; ++qsub) {
        float al = alpha_r[qsub];
        acc[dblock][qsub][0] *= al; acc[dblock][qsub][1] *= al;
        acc[dblock][qsub][2] *= al; acc[dblock][qsub][3] *= al;
        acc[dblock][qsub] = mfma32(vf, pb[qsub], acc[dblock][qsub]);
      }
    }
  }

  // ---- cross-wave combine (one-time) ----
  if (g == 0) {
#pragma unroll
    for (int qsub = 0; qsub < 4; ++qsub) {
      msh[wave][qsub * 16 + l15] = m_r[qsub];
      ssh[wave][qsub * 16 + l15] = s_r[qsub];
    }
  }
  __syncthreads();
  float fac[4], inv[4];
#pragma unroll
  for (int qsub = 0; qsub < 4; ++qsub) {
    int q = qsub * 16 + l15;
    float M = fmaxf(fmaxf(msh[0][q], msh[1][q]), fmaxf(msh[2][q], msh[3][q]));
    float St = ssh[0][q] * exp2f(msh[0][q] - M) +
               ssh[1][q] * exp2f(msh[1][q] - M) +
               ssh[2][q] * exp2f(msh[2][q] - M) +
               ssh[3][q] * exp2f(msh[3][q] - M);
    fac[qsub] = exp2f(m_r[qsub] - M);
    inv[qsub] = (St > 0.f) ? (1.f / St) : 0.f;
  }
#pragma unroll
  for (int w = 0; w < 4; ++w) {
    if (wave == w) {
#pragma unroll
      for (int dblock = 0; dblock < 4; ++dblock)
#pragma unroll
        for (int qsub = 0; qsub < 4; ++qsub)
#pragma unroll
          for (int r = 0; r < 4; ++r) {
            float v = acc[dblock][qsub][r] * fac[qsub];
            int row = dblock * 16 + g * 4 + r, col = qsub * 16 + l15;
            obuf[row][col] = (w == 0) ? v : obuf[row][col] + v;
          }
    }
    __syncthreads();
  }
  // store: d = wave*16+g*4+r (contig 4), q = qsub*16+l15
#pragma unroll
  for (int qsub = 0; qsub < 4; ++qsub) {
    float iv = inv[qsub];
    int col = qsub * 16 + l15;
    bf16x4 pk = {bfs(obuf[wave * 16 + g * 4 + 0][col] * iv),
                 bfs(obuf[wave * 16 + g * 4 + 1][col] * iv),
                 bfs(obuf[wave * 16 + g * 4 + 2][col] * iv),
                 bfs(obuf[wave * 16 + g * 4 + 3][col] * iv)};
    bf16* Op = ao + ((size_t)b * N_N + q0 + col) * 256 +
               h * 64 + wave * 16 + g * 4;
    *reinterpret_cast<bf16x4*>(Op) = pk;
  }
}

// ---------------- proj GEMM (MFMA) + bias + residual, fp32 out --------------
__global__ __launch_bounds__(256) void proj_gemm(const bf16* __restrict__ wpb,
                                                 const bf16* __restrict__ ao,
                                                 const float* __restrict__ bproj,
                                                 const float* __restrict__ x,
                                                 float* __restrict__ out) {
  int id = (blockIdx.x & 7) * 72 + (blockIdx.x >> 3);
  int nt = id % 18, ot = (id / 18) & 3, b = id / 72;
  int o0 = ot * 64, n0 = nt * 128;
  int lane = threadIdx.x & 63, wave = threadIdx.x >> 6;
  int l15 = lane & 15, g = lane >> 4, g8 = g * 8;
  const bf16* Ab = wpb + (size_t)(o0 + l15) * 256 + g8;
  const bf16* Bb = ao + ((size_t)b * N_N + n0 + wave * 32 + l15) * 256 + g8;
  f32x4 z = {0.f, 0.f, 0.f, 0.f};
  f32x4 acc[4][2];
#pragma unroll
  for (int i = 0; i < 4; ++i) { acc[i][0] = z; acc[i][1] = z; }
#pragma unroll
  for (int kk = 0; kk < 8; ++kk) {
    int co = kk * 32;
    bf16x8 b0 = *(const bf16x8*)(Bb + co);
    bf16x8 b1 = *(const bf16x8*)(Bb + 16 * 256 + co);
#pragma unroll
    for (int mb = 0; mb < 4; ++mb) {
      bf16x8 aa = *(const bf16x8*)(Ab + mb * 4096 + co);
      acc[mb][0] = mfma32(aa, b0, acc[mb][0]);
      acc[mb][1] = mfma32(aa, b1, acc[mb][1]);
    }
  }
  int jb = n0 + wave * 32;
#pragma unroll
  for (int mb = 0; mb < 4; ++mb) {
    int ob = o0 + mb * 16 + g * 4;
    f32x4 bp = *(const f32x4*)(bproj + ob);
#pragma unroll
    for (int nb = 0; nb < 2; ++nb) {
      int n = jb + nb * 16 + l15;
#pragma unroll
      for (int r = 0; r < 4; ++r) {
        size_t idx = ((size_t)b * 256 + ob + r) * N_N + n;
        out[idx] = acc[mb][nb][r] + bp[r] + x[idx];
      }
    }
  }
}

// ---------------- host launch ------------------------------------------------
extern "C" void kernel_launch(void* const* d_in, const int* in_sizes, int n_in,
                              void* d_out, int out_size, void* d_ws, size_t ws_size,
                              hipStream_t stream) {
  (void)in_sizes; (void)n_in; (void)out_size; (void)ws_size;
  const float* x     = (const float*)d_in[0];
  const int*   mask  = (const int*)d_in[1];
  const float* gnw   = (const float*)d_in[2];
  const float* gnb   = (const float*)d_in[3];
  const float* wqkv  = (const float*)d_in[4];
  const float* wproj = (const float*)d_in[5];
  const float* bproj = (const float*)d_in[6];
  float* out = (float*)d_out;
  char* ws = (char*)d_ws;

  float* part = (float*)(ws + 0);                  // 2048 B
  float* mr   = (float*)(ws + 2048);               // 64 B
  bf16*  wqb  = (bf16*)(ws + 4096);                // 393216 B
  bf16*  wpb  = (bf16*)(ws + 397312);              // 131072 B
  bf16*  xt   = (bf16*)(ws + 528384);              // 9437184 B (reused as ao)
  bf16*  qkv  = (bf16*)(ws + 9965568);             // 28311552 B -> end ~36.5 MB
  bf16*  ao   = xt;  // xt dead after qkv_mfma

  gn_stats<<<256, 256, 0, stream>>>(x, part);
  stats_final<<<1, 64, 0, stream>>>(part, mr);
  wq_conv<<<768, 256, 0, stream>>>(wqkv, wqb);
  wp_conv<<<256, 256, 0, stream>>>(wproj, wpb);
  xt_gn<<<1152, 256, 0, stream>>>(x, mr, gnw, gnb, xt);
  qkv_mfma<<<1728, 256, 0, stream>>>(wqb, xt, qkv);
  attn_reg<<<1152, 256, 0, stream>>>(qkv, mask, ao);
  proj_gemm<<<576, 256, 0, stream>>>(wpb, ao, bproj, x, out);
}

// Round 11
// 192.158 us; speedup vs baseline: 23.0108x; 1.1896x over previous
//
#include <hip/hip_runtime.h>
#include <hip/hip_bf16.h>

typedef __hip_bfloat16 bf16;
typedef short bf16x4 __attribute__((ext_vector_type(4)));
typedef short bf16x8 __attribute__((ext_vector_type(8)));
typedef float f32x4 __attribute__((ext_vector_type(4)));

#define N_B 8
#define N_C 256
#define N_H 4
#define N_N 2304
#define N_ELEM 589824   // N_C * N_N

static __device__ __forceinline__ f32x4 mfma32(bf16x8 a, bf16x8 b, f32x4 c) {
  return __builtin_amdgcn_mfma_f32_16x16x32_bf16(a, b, c, 0, 0, 0);
}
static __device__ __forceinline__ short bfs(float f) {
  union { __hip_bfloat16 h; short s; } u;
  u.h = __float2bfloat16(f);
  return u.s;
}
struct TrueT  { static constexpr bool value = true;  };
struct FalseT { static constexpr bool value = false; };

// ---------------- GN stats: partial sums per (batch, chunk) -----------------
__global__ __launch_bounds__(256) void gn_stats(const float* __restrict__ x,
                                                float* __restrict__ part) {
  int b = blockIdx.x >> 5, chunk = blockIdx.x & 31;
  const f32x4* p = (const f32x4*)(x + (size_t)b * N_ELEM + (size_t)chunk * 18432);
  float s = 0.f, ss = 0.f;
  for (int i = threadIdx.x; i < 4608; i += 256) {
    f32x4 v = p[i];
    s  += (v[0] + v[1]) + (v[2] + v[3]);
    ss += (v[0] * v[0] + v[1] * v[1]) + (v[2] * v[2] + v[3] * v[3]);
  }
  for (int off = 32; off; off >>= 1) {
    s  += __shfl_xor(s, off);
    ss += __shfl_xor(ss, off);
  }
  __shared__ float ls[8];
  int wv = threadIdx.x >> 6;
  if ((threadIdx.x & 63) == 0) { ls[wv] = s; ls[4 + wv] = ss; }
  __syncthreads();
  if (threadIdx.x == 0) {
    part[blockIdx.x * 2]     = ls[0] + ls[1] + ls[2] + ls[3];
    part[blockIdx.x * 2 + 1] = ls[4] + ls[5] + ls[6] + ls[7];
  }
}

__global__ void stats_final(const float* __restrict__ part, float* __restrict__ mr) {
  int b = threadIdx.x;
  if (b < N_B) {
    float s = 0.f, ss = 0.f;
    for (int i = 0; i < 32; ++i) {
      s  += part[b * 64 + i * 2];
      ss += part[b * 64 + i * 2 + 1];
    }
    float mean = s * (1.f / (float)N_ELEM);
    float var  = ss * (1.f / (float)N_ELEM) - mean * mean;
    mr[b * 2]     = mean;
    mr[b * 2 + 1] = rsqrtf(var + 1e-5f);
  }
}

// ---------------- mask prefix scan -> compact key indices -------------------
__global__ __launch_bounds__(256) void mask_scan(const int* __restrict__ mask,
                                                 int* __restrict__ cidx,
                                                 int* __restrict__ count) {
  int b = blockIdx.x, tid = threadIdx.x;
  const int* mb = mask + b * N_N;
  int flags[9], tot = 0;
  for (int r = 0; r < 9; ++r) {
    int f = (mb[tid * 9 + r] != 0) ? 1 : 0;
    flags[r] = f; tot += f;
  }
  __shared__ int ls[256];
  ls[tid] = tot;
  __syncthreads();
  for (int off = 1; off < 256; off <<= 1) {
    int v = (tid >= off) ? ls[tid - off] : 0;
    __syncthreads();
    ls[tid] += v;
    __syncthreads();
  }
  int pos = ls[tid] - tot;     // exclusive prefix
  int total = ls[255];
  int* cb = cidx + b * N_N;
  for (int r = 0; r < 9; ++r)
    if (flags[r]) cb[pos++] = tid * 9 + r;
  for (int j = total + tid; j < N_N; j += 256) cb[j] = 0;  // pad -> finite rows
  if (tid == 0) count[b] = total;
}

// ---------------- weight converts -------------------------------------------
__global__ __launch_bounds__(256) void wq_conv(const float* __restrict__ wq,
                                               bf16* __restrict__ wqb) {
  int i = blockIdx.x * 256 + threadIdx.x;
  int row = i >> 8;
  // Q rows: fold head_dim^-0.5 * log2(e) so softmax uses exp2
  float sc = (row < 256) ? 0.18033688011112042f : 1.0f;
  wqb[i] = __float2bfloat16(wq[i] * sc);
}

__global__ __launch_bounds__(256) void wp_conv(const float* __restrict__ wp,
                                               bf16* __restrict__ wpb) {
  int i = blockIdx.x * 256 + threadIdx.x;
  wpb[i] = __float2bfloat16(wp[i]);
}

// ---------------- fused GN + transpose: x[b][c][n] f32 -> xt[b][n][c] bf16 --
__global__ __launch_bounds__(256) void xt_gn(const float* __restrict__ x,
                                             const float* __restrict__ mr,
                                             const float* __restrict__ gnw,
                                             const float* __restrict__ gnb,
                                             bf16* __restrict__ xt) {
  int id = blockIdx.x;               // 1152 = 36nt * 4ct * 8b
  int nt = id % 36, ct = (id / 36) & 3, b = id / 144;
  float mean = mr[b * 2], rstd = mr[b * 2 + 1];
  __shared__ bf16 tile[64][65];
  int tn = threadIdx.x & 63, tq = threadIdx.x >> 6;
  const float* xp = x + (size_t)b * N_ELEM + (size_t)(ct * 64) * N_N + nt * 64;
  for (int it = 0; it < 16; ++it) {
    int c = tq * 16 + it;
    int cg = ct * 64 + c;
    float a  = rstd * gnw[cg];
    float dd = gnb[cg] - mean * a;
    tile[c][tn] = __float2bfloat16(xp[(size_t)c * N_N + tn] * a + dd);
  }
  __syncthreads();
  bf16* xo = xt + ((size_t)b * N_N + nt * 64) * 256 + ct * 64;
  for (int it = 0; it < 16; ++it) {
    int nl = tq * 16 + it;
    xo[(size_t)nl * 256 + tn] = tile[tn][nl];
  }
}

// ---------------- QKV GEMM (MFMA; K/V rows gathered via cidx) ---------------
__global__ __launch_bounds__(256) void qkv_mfma(const bf16* __restrict__ wqb,
                                                const bf16* __restrict__ xt,
                                                const int* __restrict__ cidx,
                                                bf16* __restrict__ qkv) {
  int id = (blockIdx.x & 7) * 216 + (blockIdx.x >> 3);
  int nt = id % 18, ot = (id / 18) % 12, b = id / 216;
  int o0 = ot * 64, n0 = nt * 128;
  int lane = threadIdx.x & 63, wave = threadIdx.x >> 6;
  int l15 = lane & 15, g = lane >> 4, g8 = g * 8;
  int seg = o0 >> 8, h = (o0 >> 6) & 3;
  int jb = n0 + wave * 32;
  int j0 = jb + l15, j1 = j0 + 16;
  int r0 = j0, r1 = j1;
  if (seg != 0) {                     // K/V read compacted source rows
    const int* cb = cidx + b * N_N;
    r0 = cb[j0]; r1 = cb[j1];
  }
  const bf16* Ab = wqb + (size_t)(o0 + l15) * 256 + g8;
  const bf16* B0 = xt + ((size_t)b * N_N + r0) * 256 + g8;
  const bf16* B1 = xt + ((size_t)b * N_N + r1) * 256 + g8;
  f32x4 z = {0.f, 0.f, 0.f, 0.f};
  f32x4 acc[4][2];
#pragma unroll
  for (int i = 0; i < 4; ++i) { acc[i][0] = z; acc[i][1] = z; }
#pragma unroll
  for (int kk = 0; kk < 8; ++kk) {
    int co = kk * 32;
    bf16x8 b0 = *(const bf16x8*)(B0 + co);
    bf16x8 b1 = *(const bf16x8*)(B1 + co);
#pragma unroll
    for (int mb = 0; mb < 4; ++mb) {
      bf16x8 aa = *(const bf16x8*)(Ab + mb * 4096 + co);
      acc[mb][0] = mfma32(aa, b0, acc[mb][0]);
      acc[mb][1] = mfma32(aa, b1, acc[mb][1]);
    }
  }
  bf16* Base = qkv + ((size_t)seg * (N_B * N_H) + (size_t)b * N_H + h) *
               ((size_t)N_N * 64);
  if (seg < 2) {
#pragma unroll
    for (int mb = 0; mb < 4; ++mb) {
#pragma unroll
      for (int nb = 0; nb < 2; ++nb) {
        int row = jb + nb * 16 + l15;
        int d0 = mb * 16 + g * 4;
        bf16x4 pk = {bfs(acc[mb][nb][0]), bfs(acc[mb][nb][1]),
                     bfs(acc[mb][nb][2]), bfs(acc[mb][nb][3])};
        *reinterpret_cast<bf16x4*>(Base + (size_t)row * 64 + d0) = pk;
      }
    }
  } else {
#pragma unroll
    for (int mb = 0; mb < 4; ++mb) {
#pragma unroll
      for (int nb = 0; nb < 2; ++nb) {
        int n = jb + nb * 16 + l15;
#pragma unroll
        for (int r = 0; r < 4; ++r) {
          int d = mb * 16 + g * 4 + r;
          Base[(size_t)d * N_N + n] = __float2bfloat16(acc[mb][nb][r]);
        }
      }
    }
  }
}

// ---------------- register-softmax flash attention over compact keys --------
// Wave w owns key-slots {j : j%64 in [16w,16w+16)} of the compacted list.
// Main loop barrier-free / LDS-free; T13 defer-rescale (THR=8 in log2 domain);
// tail handled by index-based masking (padded K/V rows are finite row-0 data).
__global__ __launch_bounds__(256, 2) void attn_reg(const bf16* __restrict__ qkv,
                                                   const int* __restrict__ count,
                                                   bf16* __restrict__ ao) {
  int id = (blockIdx.x & 7) * 144 + (blockIdx.x >> 3);
  int qt = id % 36, h = (id / 36) & 3, b = id / 144;
  int tid = threadIdx.x;
  int lane = tid & 63, wave = tid >> 6;
  int l15 = lane & 15, g = lane >> 4, g8 = g * 8;
  int q0 = qt * 64;
  const size_t HSZ = (size_t)N_N * 64;
  const bf16* Qb = qkv + ((size_t)b * N_H + h) * HSZ;
  const bf16* Kb = qkv + ((size_t)(N_B * N_H) + (size_t)b * N_H + h) * HSZ;
  const bf16* Vt = qkv + ((size_t)(2 * N_B * N_H) + (size_t)b * N_H + h) * HSZ;
  int cnt = count[b];

  __shared__ float msh[4][64], ssh[4][64];
  __shared__ float obuf[64][65];

  bf16x8 qf[4][2];
#pragma unroll
  for (int qsub = 0; qsub < 4; ++qsub) {
    const bf16* Qp = Qb + (size_t)(q0 + qsub * 16 + l15) * 64;
    qf[qsub][0] = *(const bf16x8*)(Qp + g8);
    qf[qsub][1] = *(const bf16x8*)(Qp + 32 + g8);
  }
  f32x4 z = {0.f, 0.f, 0.f, 0.f};
  f32x4 acc[4][4];   // [dblock][qsub]: O[d=dblock*16+g*4+r][q=qsub*16+l15]
#pragma unroll
  for (int i = 0; i < 4; ++i)
#pragma unroll
    for (int j = 0; j < 4; ++j) acc[i][j] = z;
  float m_r[4] = {-3.0e38f, -3.0e38f, -3.0e38f, -3.0e38f};
  float s_r[4] = {0.f, 0.f, 0.f, 0.f};
  int kw = wave * 16;
  const float NEG = -3.0e38f;

  auto step = [&](int kb, auto tail_t) {
    constexpr bool TAIL = decltype(tail_t)::value;
    const bf16* Kp0 = Kb + (size_t)(kb + kw + l15) * 64;
    const bf16* Kp1 = Kb + (size_t)(kb + 64 + kw + l15) * 64;
    bf16x8 k0lo = *(const bf16x8*)(Kp0 + g8);
    bf16x8 k0hi = *(const bf16x8*)(Kp0 + 32 + g8);
    bf16x8 k1lo = *(const bf16x8*)(Kp1 + g8);
    bf16x8 k1hi = *(const bf16x8*)(Kp1 + 32 + g8);
    int base0 = kb + kw + g * 4, base1 = base0 + 64;

    bf16x8 pb[4];
    float alpha_r[4];
    bool anyResc = false;
#pragma unroll
    for (int qsub = 0; qsub < 4; ++qsub) {
      f32x4 s0 = z, s1 = z;
      s0 = mfma32(k0lo, qf[qsub][0], s0);
      s0 = mfma32(k0hi, qf[qsub][1], s0);
      s1 = mfma32(k1lo, qf[qsub][0], s1);
      s1 = mfma32(k1hi, qf[qsub][1], s1);
      float a0, a1, a2, a3, a4, a5, a6, a7;
      if constexpr (TAIL) {
        a0 = (base0 + 0 < cnt) ? s0[0] : NEG;
        a1 = (base0 + 1 < cnt) ? s0[1] : NEG;
        a2 = (base0 + 2 < cnt) ? s0[2] : NEG;
        a3 = (base0 + 3 < cnt) ? s0[3] : NEG;
        a4 = (base1 + 0 < cnt) ? s1[0] : NEG;
        a5 = (base1 + 1 < cnt) ? s1[1] : NEG;
        a6 = (base1 + 2 < cnt) ? s1[2] : NEG;
        a7 = (base1 + 3 < cnt) ? s1[3] : NEG;
      } else {
        a0 = s0[0]; a1 = s0[1]; a2 = s0[2]; a3 = s0[3];
        a4 = s1[0]; a5 = s1[1]; a6 = s1[2]; a7 = s1[3];
      }
      float pmax = fmaxf(fmaxf(fmaxf(a0, a1), fmaxf(a2, a3)),
                         fmaxf(fmaxf(a4, a5), fmaxf(a6, a7)));
      pmax = fmaxf(pmax, __shfl_xor(pmax, 16));
      pmax = fmaxf(pmax, __shfl_xor(pmax, 32));
      // T13: defer rescale while max growth <= 8 (p bounded by 2^8)
      bool skip = __all(pmax - m_r[qsub] <= 8.f);
      if (skip) {
        alpha_r[qsub] = 1.f;
      } else {
        float mnew = fmaxf(m_r[qsub], pmax);
        alpha_r[qsub] = exp2f(m_r[qsub] - mnew);
        m_r[qsub] = mnew;
        anyResc = true;
      }
      float mref = m_r[qsub];
      float p0 = exp2f(a0 - mref), p1 = exp2f(a1 - mref);
      float p2 = exp2f(a2 - mref), p3 = exp2f(a3 - mref);
      float p4 = exp2f(a4 - mref), p5 = exp2f(a5 - mref);
      float p6 = exp2f(a6 - mref), p7 = exp2f(a7 - mref);
      float psum = ((p0 + p1) + (p2 + p3)) + ((p4 + p5) + (p6 + p7));
      psum += __shfl_xor(psum, 16);
      psum += __shfl_xor(psum, 32);
      s_r[qsub] = s_r[qsub] * alpha_r[qsub] + psum;
      pb[qsub] = bf16x8{bfs(p0), bfs(p1), bfs(p2), bfs(p3),
                        bfs(p4), bfs(p5), bfs(p6), bfs(p7)};
    }
    if (anyResc) {
#pragma unroll
      for (int dblock = 0; dblock < 4; ++dblock)
#pragma unroll
        for (int qsub = 0; qsub < 4; ++qsub) {
          float al = alpha_r[qsub];
          acc[dblock][qsub][0] *= al; acc[dblock][qsub][1] *= al;
          acc[dblock][qsub][2] *= al; acc[dblock][qsub][3] *= al;
        }
    }
#pragma unroll
    for (int dblock = 0; dblock < 4; ++dblock) {
      const bf16* Vp = Vt + (size_t)(dblock * 16 + l15) * N_N;
      bf16x4 v0 = *(const bf16x4*)(Vp + kb + kw + g * 4);
      bf16x4 v1 = *(const bf16x4*)(Vp + kb + 64 + kw + g * 4);
      bf16x8 vf = {v0[0], v0[1], v0[2], v0[3], v1[0], v1[1], v1[2], v1[3]};
#pragma unroll
      for (int qsub = 0; qsub < 4; ++qsub)
        acc[dblock][qsub] = mfma32(vf, pb[qsub], acc[dblock][qsub]);
    }
  };

  int kb = 0;
  for (; kb + 128 <= cnt; kb += 128) step(kb, FalseT{});
  if (kb < cnt) step(kb, TrueT{});

  // ---- cross-wave combine (one-time) ----
  if (g == 0) {
#pragma unroll
    for (int qsub = 0; qsub < 4; ++qsub) {
      msh[wave][qsub * 16 + l15] = m_r[qsub];
      ssh[wave][qsub * 16 + l15] = s_r[qsub];
    }
  }
  __syncthreads();
  float fac[4], inv[4];
#pragma unroll
  for (int qsub = 0; qsub < 4; ++qsub) {
    int q = qsub * 16 + l15;
    float M = fmaxf(fmaxf(msh[0][q], msh[1][q]), fmaxf(msh[2][q], msh[3][q]));
    float St = ssh[0][q] * exp2f(msh[0][q] - M) +
               ssh[1][q] * exp2f(msh[1][q] - M) +
               ssh[2][q] * exp2f(msh[2][q] - M) +
               ssh[3][q] * exp2f(msh[3][q] - M);
    fac[qsub] = exp2f(m_r[qsub] - M);
    inv[qsub] = (St > 0.f) ? (1.f / St) : 0.f;
  }
#pragma unroll
  for (int w = 0; w < 4; ++w) {
    if (wave == w) {
#pragma unroll
      for (int dblock = 0; dblock < 4; ++dblock)
#pragma unroll
        for (int qsub = 0; qsub < 4; ++qsub)
#pragma unroll
          for (int r = 0; r < 4; ++r) {
            float v = acc[dblock][qsub][r] * fac[qsub];
            int row = dblock * 16 + g * 4 + r, col = qsub * 16 + l15;
            obuf[row][col] = (w == 0) ? v : obuf[row][col] + v;
          }
    }
    __syncthreads();
  }
#pragma unroll
  for (int qsub = 0; qsub < 4; ++qsub) {
    float iv = inv[qsub];
    int col = qsub * 16 + l15;
    bf16x4 pk = {bfs(obuf[wave * 16 + g * 4 + 0][col] * iv),
                 bfs(obuf[wave * 16 + g * 4 + 1][col] * iv),
                 bfs(obuf[wave * 16 + g * 4 + 2][col] * iv),
                 bfs(obuf[wave * 16 + g * 4 + 3][col] * iv)};
    bf16* Op = ao + ((size_t)b * N_N + q0 + col) * 256 +
               h * 64 + wave * 16 + g * 4;
    *reinterpret_cast<bf16x4*>(Op) = pk;
  }
}

// ---------------- proj GEMM (MFMA) + bias + residual, fp32 out --------------
__global__ __launch_bounds__(256) void proj_gemm(const bf16* __restrict__ wpb,
                                                 const bf16* __restrict__ ao,
                                                 const float* __restrict__ bproj,
                                                 const float* __restrict__ x,
                                                 float* __restrict__ out) {
  int id = (blockIdx.x & 7) * 72 + (blockIdx.x >> 3);
  int nt = id % 18, ot = (id / 18) & 3, b = id / 72;
  int o0 = ot * 64, n0 = nt * 128;
  int lane = threadIdx.x & 63, wave = threadIdx.x >> 6;
  int l15 = lane & 15, g = lane >> 4, g8 = g * 8;
  const bf16* Ab = wpb + (size_t)(o0 + l15) * 256 + g8;
  const bf16* Bb = ao + ((size_t)b * N_N + n0 + wave * 32 + l15) * 256 + g8;
  f32x4 z = {0.f, 0.f, 0.f, 0.f};
  f32x4 acc[4][2];
#pragma unroll
  for (int i = 0; i < 4; ++i) { acc[i][0] = z; acc[i][1] = z; }
#pragma unroll
  for (int kk = 0; kk < 8; ++kk) {
    int co = kk * 32;
    bf16x8 b0 = *(const bf16x8*)(Bb + co);
    bf16x8 b1 = *(const bf16x8*)(Bb + 16 * 256 + co);
#pragma unroll
    for (int mb = 0; mb < 4; ++mb) {
      bf16x8 aa = *(const bf16x8*)(Ab + mb * 4096 + co);
      acc[mb][0] = mfma32(aa, b0, acc[mb][0]);
      acc[mb][1] = mfma32(aa, b1, acc[mb][1]);
    }
  }
  int jb = n0 + wave * 32;
#pragma unroll
  for (int mb = 0; mb < 4; ++mb) {
    int ob = o0 + mb * 16 + g * 4;
    f32x4 bp = *(const f32x4*)(bproj + ob);
#pragma unroll
    for (int nb = 0; nb < 2; ++nb) {
      int n = jb + nb * 16 + l15;
#pragma unroll
      for (int r = 0; r < 4; ++r) {
        size_t idx = ((size_t)b * 256 + ob + r) * N_N + n;
        out[idx] = acc[mb][nb][r] + bp[r] + x[idx];
      }
    }
  }
}

// ---------------- host launch ------------------------------------------------
extern "C" void kernel_launch(void* const* d_in, const int* in_sizes, int n_in,
                              void* d_out, int out_size, void* d_ws, size_t ws_size,
                              hipStream_t stream) {
  (void)in_sizes; (void)n_in; (void)out_size; (void)ws_size;
  const float* x     = (const float*)d_in[0];
  const int*   mask  = (const int*)d_in[1];
  const float* gnw   = (const float*)d_in[2];
  const float* gnb   = (const float*)d_in[3];
  const float* wqkv  = (const float*)d_in[4];
  const float* wproj = (const float*)d_in[5];
  const float* bproj = (const float*)d_in[6];
  float* out = (float*)d_out;
  char* ws = (char*)d_ws;

  float* part  = (float*)(ws + 0);           // 2048 B
  float* mr    = (float*)(ws + 2048);        // 64 B
  int*   count = (int*)(ws + 2112);          // 32 B
  int*   cidx  = (int*)(ws + 2560);          // 73728 B -> ends 76288
  bf16*  wqb   = (bf16*)(ws + 76288);        // 393216 B -> ends 469504
  bf16*  wpb   = (bf16*)(ws + 469504);       // 131072 B -> ends 600576
  bf16*  xt    = (bf16*)(ws + 600576);       // 9437184 B -> ends 10037760
  bf16*  qkv   = (bf16*)(ws + 10037760);     // 28311552 B -> ends ~38.3 MB
  bf16*  ao    = xt;  // xt dead after qkv_mfma

  gn_stats<<<256, 256, 0, stream>>>(x, part);
  stats_final<<<1, 64, 0, stream>>>(part, mr);
  mask_scan<<<8, 256, 0, stream>>>(mask, cidx, count);
  wq_conv<<<768, 256, 0, stream>>>(wqkv, wqb);
  wp_conv<<<256, 256, 0, stream>>>(wproj, wpb);
  xt_gn<<<1152, 256, 0, stream>>>(x, mr, gnw, gnb, xt);
  qkv_mfma<<<1728, 256, 0, stream>>>(wqb, xt, cidx, qkv);
  attn_reg<<<1152, 256, 0, stream>>>(qkv, count, ao);
  proj_gemm<<<576, 256, 0, stream>>>(wpb, ao, bproj, x, out);
}